// Round 12
// baseline (248.611 us; speedup 1.0000x reference)
//
#include <hip/hip_runtime.h>

#define D    256
#define NH   8
#define DH   32
#define NL   4
#define NP   4
#define DFF  1024
#define NQ   900
#define BS   4
#define LV   13294
#define MROWS (NQ*BS)   // 3600

typedef short bf16x8 __attribute__((ext_vector_type(8)));
typedef float f32x4  __attribute__((ext_vector_type(4)));

__device__ inline ushort f2bf(float f) {
    unsigned u = __float_as_uint(f);
    unsigned r = (u + 0x7fffu + ((u >> 16) & 1u)) >> 16;
    return (ushort)r;
}
__device__ inline float bf2f(ushort u) { return __uint_as_float(((unsigned)u) << 16); }

// ---------------- prep: x_bf = bf(tgt+pos), tgt_bf = bf(tgt) ----------------
__global__ void prep_x_kernel(const float* __restrict__ tgt, const float* __restrict__ pos,
                              ushort* __restrict__ x_bf, ushort* __restrict__ tgt_bf) {
    int i = blockIdx.x * blockDim.x + threadIdx.x;
    float4 a = *(const float4*)&tgt[(size_t)i * 4];
    float4 p = *(const float4*)&pos[(size_t)i * 4];
    ushort4 xo, to;
    to.x = f2bf(a.x); to.y = f2bf(a.y); to.z = f2bf(a.z); to.w = f2bf(a.w);
    xo.x = f2bf(a.x + p.x); xo.y = f2bf(a.y + p.y); xo.z = f2bf(a.z + p.z); xo.w = f2bf(a.w + p.w);
    *(ushort4*)&x_bf[(size_t)i * 4] = xo;
    *(ushort4*)&tgt_bf[(size_t)i * 4] = to;
}

// ---------------- weight transpose+convert: W[K][N] f32 -> Wt[N][K] bf16 ----------------
__global__ void wt_transpose_kernel(
    const float* w0, const float* w1, const float* w2, const float* w3, const float* w4,
    const float* w5, const float* w6, const float* w7, const float* w8, const float* w9,
    ushort* o0, ushort* o1, ushort* o2, ushort* o3, ushort* o4,
    ushort* o5, ushort* o6, ushort* o7, ushort* o8, ushort* o9) {
    __shared__ float Ts[32][33];
    int z = blockIdx.z;
    const float* src; ushort* dst; int K, N;
    switch (z) {
        case 0: src = w0; dst = o0; K = 256;  N = 256;  break;
        case 1: src = w1; dst = o1; K = 256;  N = 256;  break;
        case 2: src = w2; dst = o2; K = 256;  N = 256;  break;
        case 3: src = w3; dst = o3; K = 256;  N = 256;  break;
        case 4: src = w4; dst = o4; K = 256;  N = 256;  break;
        case 5: src = w5; dst = o5; K = 256;  N = 256;  break;
        case 6: src = w6; dst = o6; K = 256;  N = 128;  break;
        case 7: src = w7; dst = o7; K = 256;  N = 256;  break;
        case 8: src = w8; dst = o8; K = 256;  N = 1024; break;
        default:src = w9; dst = o9; K = 1024; N = 256;  break;
    }
    int tiles_n = N >> 5;
    int tile = blockIdx.x;
    int tx = tile % tiles_n, ty = tile / tiles_n;
    if (ty >= (K >> 5)) return;
    int n0 = tx * 32, k0 = ty * 32;
    int t = threadIdx.x;
    #pragma unroll
    for (int i = 0; i < 4; ++i) {
        int e = t + i * 256; int r = e >> 5, c = e & 31;
        Ts[r][c] = src[(size_t)(k0 + r) * N + n0 + c];
    }
    __syncthreads();
    #pragma unroll
    for (int i = 0; i < 4; ++i) {
        int e = t + i * 256; int r = e >> 5, c = e & 31;
        dst[(size_t)(n0 + r) * K + k0 + c] = f2bf(Ts[c][r]);
    }
}

// ---------------- bf16 MFMA GEMM: Y[M,N] = X[M,K] @ Wt[N,K]^T + bias ----------------
struct Job {
    const ushort* Xb;
    const float*  Xf;
    const ushort* Wt;
    const float*  bias;
    float*  Yf;
    ushort* Yb;
    int M, K, N, relu;
};

__global__ __launch_bounds__(256, 3)
void gemm_bf_kernel(Job j0, Job j1, Job j2) {
    Job j = (blockIdx.z == 0) ? j0 : (blockIdx.z == 1 ? j1 : j2);
    const int row0 = blockIdx.y * 64, col0 = blockIdx.x * 64;
    if (row0 >= j.M || col0 >= j.N) return;
    __shared__ ushort As[64 * 72];
    __shared__ ushort Bs[64 * 72];
    const int t = threadIdx.x, w = t >> 6, lane = t & 63;
    const int wr = w >> 1, wc = w & 1, l15 = lane & 15, kb = lane >> 4;

    f32x4 acc[2][2];
    #pragma unroll
    for (int i = 0; i < 2; ++i)
        #pragma unroll
        for (int jj = 0; jj < 2; ++jj) acc[i][jj] = (f32x4){0.f, 0.f, 0.f, 0.f};

    uint4 ra0, ra1, rb0, rb1;
    float4 rf0, rf1, rf2, rf3;

    auto gload = [&](int k0) {
        if (j.Xb) {
            {
                int e = t;              int row = e >> 3, c = e & 7;
                int gr = row0 + row; if (gr >= j.M) gr = j.M - 1;
                ra0 = *(const uint4*)&j.Xb[(size_t)gr * j.K + k0 + c * 8];
            }
            {
                int e = t + 256;        int row = e >> 3, c = e & 7;
                int gr = row0 + row; if (gr >= j.M) gr = j.M - 1;
                ra1 = *(const uint4*)&j.Xb[(size_t)gr * j.K + k0 + c * 8];
            }
        } else {
            {
                int e = t;              int row = e >> 4, q = e & 15;
                int gr = row0 + row; if (gr >= j.M) gr = j.M - 1;
                rf0 = *(const float4*)&j.Xf[(size_t)gr * j.K + k0 + q * 4];
            }
            {
                int e = t + 256;        int row = e >> 4, q = e & 15;
                int gr = row0 + row; if (gr >= j.M) gr = j.M - 1;
                rf1 = *(const float4*)&j.Xf[(size_t)gr * j.K + k0 + q * 4];
            }
            {
                int e = t + 512;        int row = e >> 4, q = e & 15;
                int gr = row0 + row; if (gr >= j.M) gr = j.M - 1;
                rf2 = *(const float4*)&j.Xf[(size_t)gr * j.K + k0 + q * 4];
            }
            {
                int e = t + 768;        int row = e >> 4, q = e & 15;
                int gr = row0 + row; if (gr >= j.M) gr = j.M - 1;
                rf3 = *(const float4*)&j.Xf[(size_t)gr * j.K + k0 + q * 4];
            }
        }
        {
            int e = t;                  int row = e >> 3, c = e & 7;
            rb0 = *(const uint4*)&j.Wt[(size_t)(col0 + row) * j.K + k0 + c * 8];
        }
        {
            int e = t + 256;            int row = e >> 3, c = e & 7;
            rb1 = *(const uint4*)&j.Wt[(size_t)(col0 + row) * j.K + k0 + c * 8];
        }
    };
    auto cvt4 = [](float4 f) {
        ushort4 pk;
        pk.x = f2bf(f.x); pk.y = f2bf(f.y); pk.z = f2bf(f.z); pk.w = f2bf(f.w);
        return pk;
    };
    auto lwrite = [&]() {
        if (j.Xb) {
            { int e = t;       int row = e >> 3, c = e & 7; *(uint4*)&As[row * 72 + c * 8] = ra0; }
            { int e = t + 256; int row = e >> 3, c = e & 7; *(uint4*)&As[row * 72 + c * 8] = ra1; }
        } else {
            { int e = t;       int row = e >> 4, q = e & 15; *(ushort4*)&As[row * 72 + q * 4] = cvt4(rf0); }
            { int e = t + 256; int row = e >> 4, q = e & 15; *(ushort4*)&As[row * 72 + q * 4] = cvt4(rf1); }
            { int e = t + 512; int row = e >> 4, q = e & 15; *(ushort4*)&As[row * 72 + q * 4] = cvt4(rf2); }
            { int e = t + 768; int row = e >> 4, q = e & 15; *(ushort4*)&As[row * 72 + q * 4] = cvt4(rf3); }
        }
        { int e = t;       int row = e >> 3, c = e & 7; *(uint4*)&Bs[row * 72 + c * 8] = rb0; }
        { int e = t + 256; int row = e >> 3, c = e & 7; *(uint4*)&Bs[row * 72 + c * 8] = rb1; }
    };
    auto compute = [&]() {
        bf16x8 a[2][2], b[2][2];
        #pragma unroll
        for (int i = 0; i < 2; ++i)
            #pragma unroll
            for (int kh = 0; kh < 2; ++kh)
                a[i][kh] = *(const bf16x8*)&As[(wr * 32 + i * 16 + l15) * 72 + (kh * 4 + kb) * 8];
        #pragma unroll
        for (int jj = 0; jj < 2; ++jj)
            #pragma unroll
            for (int kh = 0; kh < 2; ++kh)
                b[jj][kh] = *(const bf16x8*)&Bs[(wc * 32 + jj * 16 + l15) * 72 + (kh * 4 + kb) * 8];
        #pragma unroll
        for (int kh = 0; kh < 2; ++kh)
            #pragma unroll
            for (int i = 0; i < 2; ++i)
                #pragma unroll
                for (int jj = 0; jj < 2; ++jj)
                    acc[i][jj] = __builtin_amdgcn_mfma_f32_16x16x32_bf16(
                        a[i][kh], b[jj][kh], acc[i][jj], 0, 0, 0);
    };

    gload(0);
    lwrite();
    __syncthreads();
    const int nt = j.K >> 6;
    for (int tt = 0; tt < nt; ++tt) {
        if (tt + 1 < nt) gload((tt + 1) << 6);
        compute();
        __syncthreads();
        if (tt + 1 < nt) { lwrite(); __syncthreads(); }
    }

    if (j.Yb) {
        #pragma unroll
        for (int i = 0; i < 2; ++i) {
            #pragma unroll
            for (int jj = 0; jj < 2; ++jj) {
                int lcol = wc * 32 + jj * 16 + l15;
                float bv = j.bias[col0 + lcol];
                #pragma unroll
                for (int r = 0; r < 4; ++r) {
                    int lrow = wr * 32 + i * 16 + kb * 4 + r;
                    float vv = acc[i][jj][r] + bv;
                    if (j.relu) vv = fmaxf(vv, 0.f);
                    As[lrow * 64 + lcol] = f2bf(vv);
                }
            }
        }
        __syncthreads();
        #pragma unroll
        for (int it = 0; it < 2; ++it) {
            int idx = t + it * 256;
            int lrow = idx >> 3, c = idx & 7;
            int grow = row0 + lrow;
            if (grow < j.M)
                *(uint4*)&j.Yb[(size_t)grow * j.N + col0 + c * 8] =
                    *(const uint4*)&As[lrow * 64 + c * 8];
        }
    } else {
        #pragma unroll
        for (int i = 0; i < 2; ++i) {
            #pragma unroll
            for (int jj = 0; jj < 2; ++jj) {
                int gcol = col0 + wc * 32 + jj * 16 + l15;
                float bv = j.bias[gcol];
                #pragma unroll
                for (int r = 0; r < 4; ++r) {
                    int grow = row0 + wr * 32 + i * 16 + kb * 4 + r;
                    if (grow < j.M) {
                        float vv = acc[i][jj][r] + bv;
                        if (j.relu) vv = fmaxf(vv, 0.f);
                        j.Yf[(size_t)grow * j.N + gcol] = vv;
                    }
                }
            }
        }
    }
}

// ---------------- wide GEMM for value projection: Y[M,256] = X[M,256](f32) @ Wt^T ----------------
__global__ __launch_bounds__(512, 2)
void gemm_wide_kernel(const float* __restrict__ Xf, const ushort* __restrict__ Wt,
                      const float* __restrict__ bias, ushort* __restrict__ Yb, int M) {
    __shared__ ushort As[64 * 72];
    __shared__ ushort Bs[256 * 72];
    const int t = threadIdx.x, w = t >> 6, lane = t & 63;
    const int wr = w >> 2, wc = w & 3, l15 = lane & 15, kb = lane >> 4;
    const int row0 = blockIdx.x * 64;

    f32x4 acc[2][4];
    #pragma unroll
    for (int i = 0; i < 2; ++i)
        #pragma unroll
        for (int jj = 0; jj < 4; ++jj) acc[i][jj] = (f32x4){0.f, 0.f, 0.f, 0.f};

    float4 rf0, rf1;
    uint4 rb[4];

    auto gload = [&](int k0) {
        {
            int e = t;        int row = e >> 4, q = e & 15;
            int gr = row0 + row; if (gr >= M) gr = M - 1;
            rf0 = *(const float4*)&Xf[(size_t)gr * 256 + k0 + q * 4];
        }
        {
            int e = t + 512;  int row = e >> 4, q = e & 15;
            int gr = row0 + row; if (gr >= M) gr = M - 1;
            rf1 = *(const float4*)&Xf[(size_t)gr * 256 + k0 + q * 4];
        }
        #pragma unroll
        for (int i = 0; i < 4; ++i) {
            int e = t + i * 512; int row = e >> 3, c = e & 7;
            rb[i] = *(const uint4*)&Wt[(size_t)row * 256 + k0 + c * 8];
        }
    };
    auto cvt4 = [](float4 f) {
        ushort4 pk;
        pk.x = f2bf(f.x); pk.y = f2bf(f.y); pk.z = f2bf(f.z); pk.w = f2bf(f.w);
        return pk;
    };
    auto lwrite = [&]() {
        { int e = t;       int row = e >> 4, q = e & 15; *(ushort4*)&As[row * 72 + q * 4] = cvt4(rf0); }
        { int e = t + 512; int row = e >> 4, q = e & 15; *(ushort4*)&As[row * 72 + q * 4] = cvt4(rf1); }
        #pragma unroll
        for (int i = 0; i < 4; ++i) {
            int e = t + i * 512; int row = e >> 3, c = e & 7;
            *(uint4*)&Bs[row * 72 + c * 8] = rb[i];
        }
    };
    auto compute = [&]() {
        bf16x8 a[2][2], b[4][2];
        #pragma unroll
        for (int i = 0; i < 2; ++i)
            #pragma unroll
            for (int kh = 0; kh < 2; ++kh)
                a[i][kh] = *(const bf16x8*)&As[(wr * 32 + i * 16 + l15) * 72 + (kh * 4 + kb) * 8];
        #pragma unroll
        for (int jj = 0; jj < 4; ++jj)
            #pragma unroll
            for (int kh = 0; kh < 2; ++kh)
                b[jj][kh] = *(const bf16x8*)&Bs[(wc * 64 + jj * 16 + l15) * 72 + (kh * 4 + kb) * 8];
        #pragma unroll
        for (int kh = 0; kh < 2; ++kh)
            #pragma unroll
            for (int i = 0; i < 2; ++i)
                #pragma unroll
                for (int jj = 0; jj < 4; ++jj)
                    acc[i][jj] = __builtin_amdgcn_mfma_f32_16x16x32_bf16(
                        a[i][kh], b[jj][kh], acc[i][jj], 0, 0, 0);
    };

    gload(0);
    lwrite();
    __syncthreads();
    #pragma unroll
    for (int tt = 0; tt < 4; ++tt) {
        if (tt + 1 < 4) gload((tt + 1) << 6);
        compute();
        __syncthreads();
        if (tt + 1 < 4) { lwrite(); __syncthreads(); }
    }

    ushort* obuf = Bs;
    #pragma unroll
    for (int i = 0; i < 2; ++i) {
        #pragma unroll
        for (int jj = 0; jj < 4; ++jj) {
            int lcol = wc * 64 + jj * 16 + l15;
            float bv = bias[lcol];
            #pragma unroll
            for (int r = 0; r < 4; ++r) {
                int lrow = wr * 32 + i * 16 + kb * 4 + r;
                obuf[lrow * 256 + lcol] = f2bf(acc[i][jj][r] + bv);
            }
        }
    }
    __syncthreads();
    #pragma unroll
    for (int it = 0; it < 4; ++it) {
        int idx = t + it * 512;
        int lrow = idx >> 5, c = idx & 31;
        int grow = row0 + lrow;
        if (grow < M)
            *(uint4*)&Yb[(size_t)grow * 256 + c * 8] =
                *(const uint4*)&obuf[lrow * 256 + c * 8];
    }
}

// ---------------- fused full-width GEMM + add + LayerNorm ----------------
// Y = Xb[M,K](bf16) @ Wt[256,K]^T + bias;  out = LN(resid + Y)
// MODE 0: outf only; 1: outf + outb=bf(res); 2: outf + outb=bf(res+pos)
template<int MODE>
__global__ __launch_bounds__(512, 2)
void gemm_ln_kernel(const ushort* __restrict__ Xb, const ushort* __restrict__ Wt,
                    const float* __restrict__ bias, const float* __restrict__ resid,
                    const float* __restrict__ g, const float* __restrict__ bt,
                    float* __restrict__ outf, ushort* __restrict__ outb,
                    const float* __restrict__ pos, int M, int K) {
    __shared__ ushort As[64 * 72];
    __shared__ ushort Bs[256 * 72];   // reused as f32 staging (32KB) in epilogue
    const int t = threadIdx.x, w = t >> 6, lane = t & 63;
    const int wr = w >> 2, wc = w & 3, l15 = lane & 15, kb = lane >> 4;
    const int row0 = blockIdx.x * 64;

    f32x4 acc[2][4];
    #pragma unroll
    for (int i = 0; i < 2; ++i)
        #pragma unroll
        for (int jj = 0; jj < 4; ++jj) acc[i][jj] = (f32x4){0.f, 0.f, 0.f, 0.f};

    uint4 ra0, rb[4];

    auto gload = [&](int k0) {
        {
            int e = t; int row = e >> 3, c = e & 7;
            int gr = row0 + row; if (gr >= M) gr = M - 1;
            ra0 = *(const uint4*)&Xb[(size_t)gr * K + k0 + c * 8];
        }
        #pragma unroll
        for (int i = 0; i < 4; ++i) {
            int e = t + i * 512; int row = e >> 3, c = e & 7;
            rb[i] = *(const uint4*)&Wt[(size_t)row * K + k0 + c * 8];
        }
    };
    auto lwrite = [&]() {
        { int e = t; int row = e >> 3, c = e & 7; *(uint4*)&As[row * 72 + c * 8] = ra0; }
        #pragma unroll
        for (int i = 0; i < 4; ++i) {
            int e = t + i * 512; int row = e >> 3, c = e & 7;
            *(uint4*)&Bs[row * 72 + c * 8] = rb[i];
        }
    };
    auto compute = [&]() {
        bf16x8 a[2][2], b[4][2];
        #pragma unroll
        for (int i = 0; i < 2; ++i)
            #pragma unroll
            for (int kh = 0; kh < 2; ++kh)
                a[i][kh] = *(const bf16x8*)&As[(wr * 32 + i * 16 + l15) * 72 + (kh * 4 + kb) * 8];
        #pragma unroll
        for (int jj = 0; jj < 4; ++jj)
            #pragma unroll
            for (int kh = 0; kh < 2; ++kh)
                b[jj][kh] = *(const bf16x8*)&Bs[(wc * 64 + jj * 16 + l15) * 72 + (kh * 4 + kb) * 8];
        #pragma unroll
        for (int kh = 0; kh < 2; ++kh)
            #pragma unroll
            for (int i = 0; i < 2; ++i)
                #pragma unroll
                for (int jj = 0; jj < 4; ++jj)
                    acc[i][jj] = __builtin_amdgcn_mfma_f32_16x16x32_bf16(
                        a[i][kh], b[jj][kh], acc[i][jj], 0, 0, 0);
    };

    gload(0);
    lwrite();
    __syncthreads();
    const int nt = K >> 6;
    for (int tt = 0; tt < nt; ++tt) {
        if (tt + 1 < nt) gload((tt + 1) << 6);
        compute();
        __syncthreads();
        if (tt + 1 < nt) { lwrite(); __syncthreads(); }
    }

    // epilogue: two 32-row halves; stage f32 Y in LDS (reuse Bs), then row LN
    float* fst = (float*)Bs;
    #pragma unroll
    for (int half = 0; half < 2; ++half) {
        if (wr == half) {
            #pragma unroll
            for (int i = 0; i < 2; ++i) {
                #pragma unroll
                for (int jj = 0; jj < 4; ++jj) {
                    int col = wc * 64 + jj * 16 + l15;
                    float bv = bias[col];
                    #pragma unroll
                    for (int r = 0; r < 4; ++r) {
                        int lrow = i * 16 + kb * 4 + r;   // 0..31
                        fst[lrow * 256 + col] = acc[i][jj][r] + bv;
                    }
                }
            }
        }
        __syncthreads();
        // LN: 16 threads per row, each handles 16 cols
        int r32 = t >> 4, c0 = (t & 15) * 16;
        int grow = row0 + half * 32 + r32;
        int gr = min(grow, M - 1);
        float vals[16];
        float sum = 0.f;
        #pragma unroll
        for (int c = 0; c < 16; ++c) {
            float v = resid[(size_t)gr * 256 + c0 + c] + fst[r32 * 256 + c0 + c];
            vals[c] = v; sum += v;
        }
        #pragma unroll
        for (int msk = 1; msk <= 8; msk <<= 1) sum += __shfl_xor(sum, msk);
        float mu = sum * (1.f / 256.f);
        float s2 = 0.f;
        #pragma unroll
        for (int c = 0; c < 16; ++c) { float d = vals[c] - mu; s2 += d * d; }
        #pragma unroll
        for (int msk = 1; msk <= 8; msk <<= 1) s2 += __shfl_xor(s2, msk);
        float rstd = rsqrtf(s2 * (1.f / 256.f) + 1e-5f);
        if (grow < M) {
            #pragma unroll
            for (int c = 0; c < 16; ++c) {
                float res = (vals[c] - mu) * rstd * g[c0 + c] + bt[c0 + c];
                outf[(size_t)grow * 256 + c0 + c] = res;
                if (MODE == 1) outb[(size_t)grow * 256 + c0 + c] = f2bf(res);
                if (MODE == 2) outb[(size_t)grow * 256 + c0 + c] =
                    f2bf(res + pos[(size_t)grow * 256 + c0 + c]);
            }
        }
        __syncthreads();
    }
}

// ---------------- MFMA flash self-attention (bf16 in/out) ----------------
__global__ __launch_bounds__(256, 2)
void sa_mfma_kernel(const ushort* __restrict__ q, const ushort* __restrict__ k,
                    const ushort* __restrict__ v, ushort* __restrict__ o) {
    __shared__ ushort Qs[64 * 40];
    __shared__ ushort Ks[64 * 40];
    __shared__ ushort Vt[32 * 72];
    __shared__ ushort Pw[4 * 16 * 72];
    const int qt = blockIdx.x, h = blockIdx.y, b = blockIdx.z;
    const int q0 = qt * 64, t = threadIdx.x;
    const int w = t >> 6, lane = t & 63;
    const int l15 = lane & 15, kb = lane >> 4;
    const float scale = 0.17677669529663687f;

    {
        int row = t >> 2, c = t & 3;
        int qn = min(q0 + row, NQ - 1);
        *(uint4*)&Qs[row * 40 + c * 8] =
            *(const uint4*)&q[((size_t)qn * BS + b) * D + h * DH + c * 8];
    }
    float m_run[4], l_run[4];
    #pragma unroll
    for (int r = 0; r < 4; ++r) { m_run[r] = -1e30f; l_run[r] = 0.f; }
    f32x4 oacc[2];
    oacc[0] = (f32x4){0.f, 0.f, 0.f, 0.f};
    oacc[1] = (f32x4){0.f, 0.f, 0.f, 0.f};
    __syncthreads();

    for (int k0 = 0; k0 < NQ; k0 += 64) {
        {
            int row = t >> 2, c = t & 3;
            int kn = min(k0 + row, NQ - 1);
            *(uint4*)&Ks[row * 40 + c * 8] =
                *(const uint4*)&k[((size_t)kn * BS + b) * D + h * DH + c * 8];
            uint4 vv = *(const uint4*)&v[((size_t)kn * BS + b) * D + h * DH + c * 8];
            ushort* pv = (ushort*)&vv;
            #pragma unroll
            for (int u = 0; u < 8; ++u) Vt[(c * 8 + u) * 72 + row] = pv[u];
        }
        __syncthreads();

        bf16x8 aq = *(const bf16x8*)&Qs[(w * 16 + l15) * 40 + kb * 8];
        f32x4 sacc[4];
        #pragma unroll
        for (int jj = 0; jj < 4; ++jj) {
            bf16x8 bk = *(const bf16x8*)&Ks[(jj * 16 + l15) * 40 + kb * 8];
            sacc[jj] = __builtin_amdgcn_mfma_f32_16x16x32_bf16(
                aq, bk, (f32x4){0.f, 0.f, 0.f, 0.f}, 0, 0, 0);
        }
        int kvalid = NQ - k0;
        #pragma unroll
        for (int jj = 0; jj < 4; ++jj) {
            #pragma unroll
            for (int r = 0; r < 4; ++r) sacc[jj][r] *= scale;
            if (jj * 16 + l15 >= kvalid) {
                #pragma unroll
                for (int r = 0; r < 4; ++r) sacc[jj][r] = -1e30f;
            }
        }
        float tm[4];
        #pragma unroll
        for (int r = 0; r < 4; ++r)
            tm[r] = fmaxf(fmaxf(sacc[0][r], sacc[1][r]), fmaxf(sacc[2][r], sacc[3][r]));
        #pragma unroll
        for (int msk = 1; msk <= 8; msk <<= 1)
            #pragma unroll
            for (int r = 0; r < 4; ++r) tm[r] = fmaxf(tm[r], __shfl_xor(tm[r], msk));
        float scl[4], newm[4];
        #pragma unroll
        for (int r = 0; r < 4; ++r) {
            newm[r] = fmaxf(m_run[r], tm[r]);
            scl[r] = __expf(m_run[r] - newm[r]);
            m_run[r] = newm[r];
        }
        float ps[4] = {0.f, 0.f, 0.f, 0.f};
        #pragma unroll
        for (int jj = 0; jj < 4; ++jj) {
            #pragma unroll
            for (int r = 0; r < 4; ++r) {
                float p = __expf(sacc[jj][r] - newm[r]);
                ps[r] += p;
                Pw[w * 1152 + (kb * 4 + r) * 72 + jj * 16 + l15] = f2bf(p);
            }
        }
        #pragma unroll
        for (int msk = 1; msk <= 8; msk <<= 1)
            #pragma unroll
            for (int r = 0; r < 4; ++r) ps[r] += __shfl_xor(ps[r], msk);
        #pragma unroll
        for (int r = 0; r < 4; ++r) l_run[r] = l_run[r] * scl[r] + ps[r];
        #pragma unroll
        for (int df = 0; df < 2; ++df)
            #pragma unroll
            for (int r = 0; r < 4; ++r) oacc[df][r] *= scl[r];
        #pragma unroll
        for (int hf = 0; hf < 2; ++hf) {
            bf16x8 pa = *(const bf16x8*)&Pw[w * 1152 + l15 * 72 + hf * 32 + kb * 8];
            #pragma unroll
            for (int df = 0; df < 2; ++df) {
                bf16x8 vb = *(const bf16x8*)&Vt[(df * 16 + l15) * 72 + hf * 32 + kb * 8];
                oacc[df] = __builtin_amdgcn_mfma_f32_16x16x32_bf16(pa, vb, oacc[df], 0, 0, 0);
            }
        }
        __syncthreads();
    }
    #pragma unroll
    for (int df = 0; df < 2; ++df) {
        #pragma unroll
        for (int r = 0; r < 4; ++r) {
            int qg = q0 + w * 16 + kb * 4 + r;
            if (qg < NQ)
                o[((size_t)qg * BS + b) * D + h * DH + df * 16 + l15] =
                    f2bf(oacc[df][r] / l_run[r]);
        }
    }
}

// ---------------- deformable sampling: 2-phase (precompute addr/weights, then gather) ----------------
__global__ __launch_bounds__(256, 8)
void deform_kernel(const ushort* __restrict__ value, const float* __restrict__ offs,
                   const float* __restrict__ aw, const float* __restrict__ refp,
                   const int* __restrict__ shapes, const int* __restrict__ lsi,
                   ushort* __restrict__ outb) {
    int n = blockIdx.x, b = blockIdx.y;
    int t = threadIdx.x;
    int m = n * BS + b;
    __shared__ float awn[NH * 16];
    __shared__ int4  sadr[128];
    __shared__ float4 swt[128];
    if (t < NH) {
        const float* p = aw + (size_t)m * 128 + t * 16;
        float mx = p[0];
        #pragma unroll
        for (int jj = 1; jj < 16; ++jj) mx = fmaxf(mx, p[jj]);
        float e[16], s = 0.f;
        #pragma unroll
        for (int jj = 0; jj < 16; ++jj) { e[jj] = __expf(p[jj] - mx); s += e[jj]; }
        float inv = 1.f / s;
        #pragma unroll
        for (int jj = 0; jj < 16; ++jj) awn[t * 16 + jj] = e[jj] * inv;
    }
    __syncthreads();
    if (t < 128) {
        int h = t >> 4, l = (t >> 2) & 3, p = t & 3;
        int Hl = shapes[l * 2], Wl = shapes[l * 2 + 1], s = lsi[l];
        float Wf = (float)Wl, Hf = (float)Hl;
        float rx = refp[(m * NL + l) * 2 + 0];
        float ry = refp[(m * NL + l) * 2 + 1];
        int oc = ((h * NL + l) * NP + p) * 2;
        float ox = offs[m * 256 + oc];
        float oy = offs[m * 256 + oc + 1];
        float ww = awn[h * 16 + l * NP + p];
        float x = (rx + ox / Wf) * Wf - 0.5f;
        float y = (ry + oy / Hf) * Hf - 0.5f;
        float x0 = floorf(x), y0 = floorf(y);
        float lx = x - x0, ly = y - y0;
        int xi = (int)x0, yi = (int)y0;
        int4 a4; float4 w4;
        int* ap = (int*)&a4; float* wp = (float*)&w4;
        #pragma unroll
        for (int cy = 0; cy < 2; ++cy) {
            #pragma unroll
            for (int cx = 0; cx < 2; ++cx) {
                int xx = xi + cx, yy = yi + cy;
                bool valid = (xx >= 0 && xx < Wl && yy >= 0 && yy < Hl);
                float cw = (cx ? lx : 1.f - lx) * (cy ? ly : 1.f - ly);
                ap[cy * 2 + cx] = valid ? (int)(((size_t)(s + yy * Wl + xx) * BS + b) * D + h * DH) : 0;
                wp[cy * 2 + cx] = valid ? ww * cw : 0.f;
            }
        }
        sadr[t] = a4;
        swt[t] = w4;
    }
    __syncthreads();
    int h = t >> 5, dh = t & 31;
    float acc = 0.f;
    #pragma unroll
    for (int i = 0; i < 16; ++i) {
        int4 a4 = sadr[h * 16 + i];
        float4 w4 = swt[h * 16 + i];
        acc += w4.x * bf2f(value[a4.x + dh]);
        acc += w4.y * bf2f(value[a4.y + dh]);
        acc += w4.z * bf2f(value[a4.z + dh]);
        acc += w4.w * bf2f(value[a4.w + dh]);
    }
    outb[m * D + h * DH + dh] = f2bf(acc);
}

extern "C" void kernel_launch(void* const* d_in, const int* in_sizes, int n_in,
                              void* d_out, int out_size, void* d_ws, size_t ws_size,
                              hipStream_t stream) {
    const float* tgt    = (const float*)d_in[0];
    const float* pos    = (const float*)d_in[1];
    const float* refp   = (const float*)d_in[2];
    const float* memory = (const float*)d_in[3];
    const int*   shapes = (const int*)d_in[4];
    const int*   lsi    = (const int*)d_in[5];
    const float* sa_wq = (const float*)d_in[6],  *sa_bq = (const float*)d_in[7];
    const float* sa_wk = (const float*)d_in[8],  *sa_bk = (const float*)d_in[9];
    const float* sa_wv = (const float*)d_in[10], *sa_bv = (const float*)d_in[11];
    const float* sa_wo = (const float*)d_in[12], *sa_bo = (const float*)d_in[13];
    const float* ln2_g = (const float*)d_in[14], *ln2_b = (const float*)d_in[15];
    const float* ca_wval = (const float*)d_in[16], *ca_bval = (const float*)d_in[17];
    const float* ca_woff = (const float*)d_in[18], *ca_boff = (const float*)d_in[19];
    const float* ca_wattn = (const float*)d_in[20], *ca_battn = (const float*)d_in[21];
    const float* ca_wout = (const float*)d_in[22], *ca_bout = (const float*)d_in[23];
    const float* ln1_g = (const float*)d_in[24], *ln1_b = (const float*)d_in[25];
    const float* ffn_w1 = (const float*)d_in[26], *ffn_b1 = (const float*)d_in[27];
    const float* ffn_w2 = (const float*)d_in[28], *ffn_b2 = (const float*)d_in[29];
    const float* ln3_g = (const float*)d_in[30], *ln3_b = (const float*)d_in[31];
    float* out = (float*)d_out;

    // ---- workspace: bf16 area then f32 area ----
    ushort* wt = (ushort*)d_ws;
    ushort* wtq   = wt + 0;
    ushort* wtk   = wt + 65536;
    ushort* wtv   = wt + 131072;
    ushort* wto   = wt + 196608;
    ushort* wtval = wt + 262144;
    ushort* wtoff = wt + 327680;
    ushort* wtattn= wt + 393216;
    ushort* wtout = wt + 425984;
    ushort* wtf1  = wt + 491520;
    ushort* wtf2  = wt + 753664;
    const size_t MD = (size_t)MROWS * D;
    ushort* x_bf   = wt + 1015808;
    ushort* tgt_bf = x_bf + MD;
    ushort* q_bf   = tgt_bf + MD;
    ushort* k_bf   = q_bf + MD;
    ushort* v_bf   = k_bf + MD;
    ushort* o_bf   = v_bf + MD;
    ushort* value_bf = o_bf + MD;
    ushort* query_bf = x_bf;
    ushort* samp_bf  = tgt_bf;
    ushort* tgt2_bf  = q_bf;
    ushort* hbuf_bf  = value_bf;
    float* fws = (float*)(value_bf + (size_t)LV * BS * D);
    float* xo   = fws;
    float* tgt1 = xo + MD;
    float* tgt2 = tgt1 + MD;
    float* offs = tgt2 + MD;
    float* aw   = offs + MD;
    (void)ws_size; (void)in_sizes; (void)n_in; (void)out_size;

    dim3 b256(256);
    Job jz = {};
    auto mkb = [](const ushort* Xb, const ushort* Wt, const float* bias,
                  float* Yf, ushort* Yb, int M, int K, int N, int relu) {
        Job j; j.Xb = Xb; j.Xf = nullptr; j.Wt = Wt; j.bias = bias;
        j.Yf = Yf; j.Yb = Yb; j.M = M; j.K = K; j.N = N; j.relu = relu; return j;
    };

    // 1. weights
    wt_transpose_kernel<<<dim3(256, 1, 10), b256, 0, stream>>>(
        sa_wq, sa_wk, sa_wv, sa_wo, ca_wval, ca_woff, ca_wattn, ca_wout, ffn_w1, ffn_w2,
        wtq, wtk, wtv, wto, wtval, wtoff, wtattn, wtout, wtf1, wtf2);
    // 2. value projection FIRST (clean L2 window; write-back overlaps later compute)
    gemm_wide_kernel<<<dim3((LV * BS + 63) / 64), dim3(512), 0, stream>>>(
        memory, wtval, ca_bval, value_bf, LV * BS);
    // 3. activations -> bf16
    prep_x_kernel<<<dim3(MD / 4 / 256), b256, 0, stream>>>(tgt, pos, x_bf, tgt_bf);
    // 4. q,k,v projections (batched)
    gemm_bf_kernel<<<dim3(4, 57, 3), b256, 0, stream>>>(
        mkb(x_bf, wtq, sa_bq, nullptr, q_bf, MROWS, D, D, 0),
        mkb(x_bf, wtk, sa_bk, nullptr, k_bf, MROWS, D, D, 0),
        mkb(tgt_bf, wtv, sa_bv, nullptr, v_bf, MROWS, D, D, 0));
    // 5. self attention
    sa_mfma_kernel<<<dim3(15, NH, BS), b256, 0, stream>>>(q_bf, k_bf, v_bf, o_bf);
    // 6. o-projection + LN2 fused (+ query_bf = bf(ln + pos))
    gemm_ln_kernel<2><<<dim3(57), dim3(512), 0, stream>>>(
        o_bf, wto, sa_bo, tgt, ln2_g, ln2_b, tgt1, query_bf, pos, MROWS, D);
    // 7. offsets + attention weights (batched; softmax fused into deform)
    gemm_bf_kernel<<<dim3(4, 57, 2), b256, 0, stream>>>(
        mkb(query_bf, wtoff, ca_boff, offs, nullptr, MROWS, D, 256, 0),
        mkb(query_bf, wtattn, ca_battn, aw, nullptr, MROWS, D, 128, 0), jz);
    // 8. deformable sampling (softmax inside, 2-phase)
    deform_kernel<<<dim3(NQ, BS), b256, 0, stream>>>(value_bf, offs, aw, refp, shapes, lsi, samp_bf);
    // 9. out-projection + LN1 fused (+ tgt2_bf)
    gemm_ln_kernel<1><<<dim3(57), dim3(512), 0, stream>>>(
        samp_bf, wtout, ca_bout, tgt1, ln1_g, ln1_b, tgt2, tgt2_bf, nullptr, MROWS, D);
    // 10. FFN1 (relu, bf16 out)
    gemm_bf_kernel<<<dim3(16, 57, 1), b256, 0, stream>>>(
        mkb(tgt2_bf, wtf1, ffn_b1, nullptr, hbuf_bf, MROWS, D, DFF, 1), jz, jz);
    // 11. FFN2 + LN3 fused -> out
    gemm_ln_kernel<0><<<dim3(57), dim3(512), 0, stream>>>(
        hbuf_bf, wtf2, ffn_b2, tgt2, ln3_g, ln3_b, out, nullptr, nullptr, MROWS, DFF);
}

// Round 13
// 215.666 us; speedup vs baseline: 1.1528x; 1.1528x over previous
//
#include <hip/hip_runtime.h>

#define D    256
#define NH   8
#define DH   32
#define NL   4
#define NP   4
#define DFF  1024
#define NQ   900
#define BS   4
#define LV   13294
#define MROWS (NQ*BS)   // 3600

typedef short bf16x8 __attribute__((ext_vector_type(8)));
typedef float f32x4  __attribute__((ext_vector_type(4)));

__device__ inline ushort f2bf(float f) {
    unsigned u = __float_as_uint(f);
    unsigned r = (u + 0x7fffu + ((u >> 16) & 1u)) >> 16;
    return (ushort)r;
}
__device__ inline float bf2f(ushort u) { return __uint_as_float(((unsigned)u) << 16); }

// ---------------- prep: x_bf = bf(tgt+pos), tgt_bf = bf(tgt) ----------------
__global__ void prep_x_kernel(const float* __restrict__ tgt, const float* __restrict__ pos,
                              ushort* __restrict__ x_bf, ushort* __restrict__ tgt_bf) {
    int i = blockIdx.x * blockDim.x + threadIdx.x;
    float4 a = *(const float4*)&tgt[(size_t)i * 4];
    float4 p = *(const float4*)&pos[(size_t)i * 4];
    ushort4 xo, to;
    to.x = f2bf(a.x); to.y = f2bf(a.y); to.z = f2bf(a.z); to.w = f2bf(a.w);
    xo.x = f2bf(a.x + p.x); xo.y = f2bf(a.y + p.y); xo.z = f2bf(a.z + p.z); xo.w = f2bf(a.w + p.w);
    *(ushort4*)&x_bf[(size_t)i * 4] = xo;
    *(ushort4*)&tgt_bf[(size_t)i * 4] = to;
}

// ---------------- weight transpose+convert: W[K][N] f32 -> Wt[N][K] bf16 ----------------
__global__ void wt_transpose_kernel(
    const float* w0, const float* w1, const float* w2, const float* w3, const float* w4,
    const float* w5, const float* w6, const float* w7, const float* w8, const float* w9,
    ushort* o0, ushort* o1, ushort* o2, ushort* o3, ushort* o4,
    ushort* o5, ushort* o6, ushort* o7, ushort* o8, ushort* o9) {
    __shared__ float Ts[32][33];
    int z = blockIdx.z;
    const float* src; ushort* dst; int K, N;
    switch (z) {
        case 0: src = w0; dst = o0; K = 256;  N = 256;  break;
        case 1: src = w1; dst = o1; K = 256;  N = 256;  break;
        case 2: src = w2; dst = o2; K = 256;  N = 256;  break;
        case 3: src = w3; dst = o3; K = 256;  N = 256;  break;
        case 4: src = w4; dst = o4; K = 256;  N = 256;  break;
        case 5: src = w5; dst = o5; K = 256;  N = 256;  break;
        case 6: src = w6; dst = o6; K = 256;  N = 128;  break;
        case 7: src = w7; dst = o7; K = 256;  N = 256;  break;
        case 8: src = w8; dst = o8; K = 256;  N = 1024; break;
        default:src = w9; dst = o9; K = 1024; N = 256;  break;
    }
    int tiles_n = N >> 5;
    int tile = blockIdx.x;
    int tx = tile % tiles_n, ty = tile / tiles_n;
    if (ty >= (K >> 5)) return;
    int n0 = tx * 32, k0 = ty * 32;
    int t = threadIdx.x;
    #pragma unroll
    for (int i = 0; i < 4; ++i) {
        int e = t + i * 256; int r = e >> 5, c = e & 31;
        Ts[r][c] = src[(size_t)(k0 + r) * N + n0 + c];
    }
    __syncthreads();
    #pragma unroll
    for (int i = 0; i < 4; ++i) {
        int e = t + i * 256; int r = e >> 5, c = e & 31;
        dst[(size_t)(n0 + r) * K + k0 + c] = f2bf(Ts[c][r]);
    }
}

// ---------------- bf16 MFMA GEMM: Y[M,N] = X[M,K] @ Wt[N,K]^T + bias ----------------
struct Job {
    const ushort* Xb;
    const float*  Xf;
    const ushort* Wt;
    const float*  bias;
    float*  Yf;
    ushort* Yb;
    int M, K, N, relu;
};

__global__ __launch_bounds__(256, 3)
void gemm_bf_kernel(Job j0, Job j1, Job j2) {
    Job j = (blockIdx.z == 0) ? j0 : (blockIdx.z == 1 ? j1 : j2);
    const int row0 = blockIdx.y * 64, col0 = blockIdx.x * 64;
    if (row0 >= j.M || col0 >= j.N) return;
    __shared__ ushort As[64 * 72];
    __shared__ ushort Bs[64 * 72];
    const int t = threadIdx.x, w = t >> 6, lane = t & 63;
    const int wr = w >> 1, wc = w & 1, l15 = lane & 15, kb = lane >> 4;

    f32x4 acc[2][2];
    #pragma unroll
    for (int i = 0; i < 2; ++i)
        #pragma unroll
        for (int jj = 0; jj < 2; ++jj) acc[i][jj] = (f32x4){0.f, 0.f, 0.f, 0.f};

    uint4 ra0, ra1, rb0, rb1;
    float4 rf0, rf1, rf2, rf3;

    auto gload = [&](int k0) {
        if (j.Xb) {
            {
                int e = t;              int row = e >> 3, c = e & 7;
                int gr = row0 + row; if (gr >= j.M) gr = j.M - 1;
                ra0 = *(const uint4*)&j.Xb[(size_t)gr * j.K + k0 + c * 8];
            }
            {
                int e = t + 256;        int row = e >> 3, c = e & 7;
                int gr = row0 + row; if (gr >= j.M) gr = j.M - 1;
                ra1 = *(const uint4*)&j.Xb[(size_t)gr * j.K + k0 + c * 8];
            }
        } else {
            {
                int e = t;              int row = e >> 4, q = e & 15;
                int gr = row0 + row; if (gr >= j.M) gr = j.M - 1;
                rf0 = *(const float4*)&j.Xf[(size_t)gr * j.K + k0 + q * 4];
            }
            {
                int e = t + 256;        int row = e >> 4, q = e & 15;
                int gr = row0 + row; if (gr >= j.M) gr = j.M - 1;
                rf1 = *(const float4*)&j.Xf[(size_t)gr * j.K + k0 + q * 4];
            }
            {
                int e = t + 512;        int row = e >> 4, q = e & 15;
                int gr = row0 + row; if (gr >= j.M) gr = j.M - 1;
                rf2 = *(const float4*)&j.Xf[(size_t)gr * j.K + k0 + q * 4];
            }
            {
                int e = t + 768;        int row = e >> 4, q = e & 15;
                int gr = row0 + row; if (gr >= j.M) gr = j.M - 1;
                rf3 = *(const float4*)&j.Xf[(size_t)gr * j.K + k0 + q * 4];
            }
        }
        {
            int e = t;                  int row = e >> 3, c = e & 7;
            rb0 = *(const uint4*)&j.Wt[(size_t)(col0 + row) * j.K + k0 + c * 8];
        }
        {
            int e = t + 256;            int row = e >> 3, c = e & 7;
            rb1 = *(const uint4*)&j.Wt[(size_t)(col0 + row) * j.K + k0 + c * 8];
        }
    };
    auto cvt4 = [](float4 f) {
        ushort4 pk;
        pk.x = f2bf(f.x); pk.y = f2bf(f.y); pk.z = f2bf(f.z); pk.w = f2bf(f.w);
        return pk;
    };
    auto lwrite = [&]() {
        if (j.Xb) {
            { int e = t;       int row = e >> 3, c = e & 7; *(uint4*)&As[row * 72 + c * 8] = ra0; }
            { int e = t + 256; int row = e >> 3, c = e & 7; *(uint4*)&As[row * 72 + c * 8] = ra1; }
        } else {
            { int e = t;       int row = e >> 4, q = e & 15; *(ushort4*)&As[row * 72 + q * 4] = cvt4(rf0); }
            { int e = t + 256; int row = e >> 4, q = e & 15; *(ushort4*)&As[row * 72 + q * 4] = cvt4(rf1); }
            { int e = t + 512; int row = e >> 4, q = e & 15; *(ushort4*)&As[row * 72 + q * 4] = cvt4(rf2); }
            { int e = t + 768; int row = e >> 4, q = e & 15; *(ushort4*)&As[row * 72 + q * 4] = cvt4(rf3); }
        }
        { int e = t;       int row = e >> 3, c = e & 7; *(uint4*)&Bs[row * 72 + c * 8] = rb0; }
        { int e = t + 256; int row = e >> 3, c = e & 7; *(uint4*)&Bs[row * 72 + c * 8] = rb1; }
    };
    auto compute = [&]() {
        bf16x8 a[2][2], b[2][2];
        #pragma unroll
        for (int i = 0; i < 2; ++i)
            #pragma unroll
            for (int kh = 0; kh < 2; ++kh)
                a[i][kh] = *(const bf16x8*)&As[(wr * 32 + i * 16 + l15) * 72 + (kh * 4 + kb) * 8];
        #pragma unroll
        for (int jj = 0; jj < 2; ++jj)
            #pragma unroll
            for (int kh = 0; kh < 2; ++kh)
                b[jj][kh] = *(const bf16x8*)&Bs[(wc * 32 + jj * 16 + l15) * 72 + (kh * 4 + kb) * 8];
        #pragma unroll
        for (int kh = 0; kh < 2; ++kh)
            #pragma unroll
            for (int i = 0; i < 2; ++i)
                #pragma unroll
                for (int jj = 0; jj < 2; ++jj)
                    acc[i][jj] = __builtin_amdgcn_mfma_f32_16x16x32_bf16(
                        a[i][kh], b[jj][kh], acc[i][jj], 0, 0, 0);
    };

    gload(0);
    lwrite();
    __syncthreads();
    const int nt = j.K >> 6;
    for (int tt = 0; tt < nt; ++tt) {
        if (tt + 1 < nt) gload((tt + 1) << 6);
        compute();
        __syncthreads();
        if (tt + 1 < nt) { lwrite(); __syncthreads(); }
    }

    if (j.Yb) {
        #pragma unroll
        for (int i = 0; i < 2; ++i) {
            #pragma unroll
            for (int jj = 0; jj < 2; ++jj) {
                int lcol = wc * 32 + jj * 16 + l15;
                float bv = j.bias[col0 + lcol];
                #pragma unroll
                for (int r = 0; r < 4; ++r) {
                    int lrow = wr * 32 + i * 16 + kb * 4 + r;
                    float vv = acc[i][jj][r] + bv;
                    if (j.relu) vv = fmaxf(vv, 0.f);
                    As[lrow * 64 + lcol] = f2bf(vv);
                }
            }
        }
        __syncthreads();
        #pragma unroll
        for (int it = 0; it < 2; ++it) {
            int idx = t + it * 256;
            int lrow = idx >> 3, c = idx & 7;
            int grow = row0 + lrow;
            if (grow < j.M)
                *(uint4*)&j.Yb[(size_t)grow * j.N + col0 + c * 8] =
                    *(const uint4*)&As[lrow * 64 + c * 8];
        }
    } else {
        #pragma unroll
        for (int i = 0; i < 2; ++i) {
            #pragma unroll
            for (int jj = 0; jj < 2; ++jj) {
                int gcol = col0 + wc * 32 + jj * 16 + l15;
                float bv = j.bias[gcol];
                #pragma unroll
                for (int r = 0; r < 4; ++r) {
                    int grow = row0 + wr * 32 + i * 16 + kb * 4 + r;
                    if (grow < j.M) {
                        float vv = acc[i][jj][r] + bv;
                        if (j.relu) vv = fmaxf(vv, 0.f);
                        j.Yf[(size_t)grow * j.N + gcol] = vv;
                    }
                }
            }
        }
    }
}

// ---------------- wide GEMM for value projection: Y[M,256] = X[M,256](f32) @ Wt^T ----------------
__global__ __launch_bounds__(512, 2)
void gemm_wide_kernel(const float* __restrict__ Xf, const ushort* __restrict__ Wt,
                      const float* __restrict__ bias, ushort* __restrict__ Yb, int M) {
    __shared__ ushort As[64 * 72];
    __shared__ ushort Bs[256 * 72];
    const int t = threadIdx.x, w = t >> 6, lane = t & 63;
    const int wr = w >> 2, wc = w & 3, l15 = lane & 15, kb = lane >> 4;
    const int row0 = blockIdx.x * 64;

    f32x4 acc[2][4];
    #pragma unroll
    for (int i = 0; i < 2; ++i)
        #pragma unroll
        for (int jj = 0; jj < 4; ++jj) acc[i][jj] = (f32x4){0.f, 0.f, 0.f, 0.f};

    float4 rf0, rf1;
    uint4 rb[4];

    auto gload = [&](int k0) {
        {
            int e = t;        int row = e >> 4, q = e & 15;
            int gr = row0 + row; if (gr >= M) gr = M - 1;
            rf0 = *(const float4*)&Xf[(size_t)gr * 256 + k0 + q * 4];
        }
        {
            int e = t + 512;  int row = e >> 4, q = e & 15;
            int gr = row0 + row; if (gr >= M) gr = M - 1;
            rf1 = *(const float4*)&Xf[(size_t)gr * 256 + k0 + q * 4];
        }
        #pragma unroll
        for (int i = 0; i < 4; ++i) {
            int e = t + i * 512; int row = e >> 3, c = e & 7;
            rb[i] = *(const uint4*)&Wt[(size_t)row * 256 + k0 + c * 8];
        }
    };
    auto cvt4 = [](float4 f) {
        ushort4 pk;
        pk.x = f2bf(f.x); pk.y = f2bf(f.y); pk.z = f2bf(f.z); pk.w = f2bf(f.w);
        return pk;
    };
    auto lwrite = [&]() {
        { int e = t;       int row = e >> 4, q = e & 15; *(ushort4*)&As[row * 72 + q * 4] = cvt4(rf0); }
        { int e = t + 512; int row = e >> 4, q = e & 15; *(ushort4*)&As[row * 72 + q * 4] = cvt4(rf1); }
        #pragma unroll
        for (int i = 0; i < 4; ++i) {
            int e = t + i * 512; int row = e >> 3, c = e & 7;
            *(uint4*)&Bs[row * 72 + c * 8] = rb[i];
        }
    };
    auto compute = [&]() {
        bf16x8 a[2][2], b[4][2];
        #pragma unroll
        for (int i = 0; i < 2; ++i)
            #pragma unroll
            for (int kh = 0; kh < 2; ++kh)
                a[i][kh] = *(const bf16x8*)&As[(wr * 32 + i * 16 + l15) * 72 + (kh * 4 + kb) * 8];
        #pragma unroll
        for (int jj = 0; jj < 4; ++jj)
            #pragma unroll
            for (int kh = 0; kh < 2; ++kh)
                b[jj][kh] = *(const bf16x8*)&Bs[(wc * 64 + jj * 16 + l15) * 72 + (kh * 4 + kb) * 8];
        #pragma unroll
        for (int kh = 0; kh < 2; ++kh)
            #pragma unroll
            for (int i = 0; i < 2; ++i)
                #pragma unroll
                for (int jj = 0; jj < 4; ++jj)
                    acc[i][jj] = __builtin_amdgcn_mfma_f32_16x16x32_bf16(
                        a[i][kh], b[jj][kh], acc[i][jj], 0, 0, 0);
    };

    gload(0);
    lwrite();
    __syncthreads();
    #pragma unroll
    for (int tt = 0; tt < 4; ++tt) {
        if (tt + 1 < 4) gload((tt + 1) << 6);
        compute();
        __syncthreads();
        if (tt + 1 < 4) { lwrite(); __syncthreads(); }
    }

    // stage 64x256 bf16 output tile in LDS (reuse Bs), then coalesced stores
    ushort* obuf = Bs;
    #pragma unroll
    for (int i = 0; i < 2; ++i) {
        #pragma unroll
        for (int jj = 0; jj < 4; ++jj) {
            int lcol = wc * 64 + jj * 16 + l15;
            float bv = bias[lcol];
            #pragma unroll
            for (int r = 0; r < 4; ++r) {
                int lrow = wr * 32 + i * 16 + kb * 4 + r;
                obuf[lrow * 256 + lcol] = f2bf(acc[i][jj][r] + bv);
            }
        }
    }
    __syncthreads();
    #pragma unroll
    for (int it = 0; it < 4; ++it) {
        int idx = t + it * 512;
        int lrow = idx >> 5, c = idx & 31;
        int grow = row0 + lrow;
        if (grow < M)
            *(uint4*)&Yb[(size_t)grow * 256 + c * 8] =
                *(const uint4*)&obuf[lrow * 256 + c * 8];
    }
}

// ---------------- MFMA flash self-attention (bf16 in/out) ----------------
__global__ __launch_bounds__(256, 2)
void sa_mfma_kernel(const ushort* __restrict__ q, const ushort* __restrict__ k,
                    const ushort* __restrict__ v, ushort* __restrict__ o) {
    __shared__ ushort Qs[64 * 40];
    __shared__ ushort Ks[64 * 40];
    __shared__ ushort Vt[32 * 72];
    __shared__ ushort Pw[4 * 16 * 72];
    const int qt = blockIdx.x, h = blockIdx.y, b = blockIdx.z;
    const int q0 = qt * 64, t = threadIdx.x;
    const int w = t >> 6, lane = t & 63;
    const int l15 = lane & 15, kb = lane >> 4;
    const float scale = 0.17677669529663687f;

    {
        int row = t >> 2, c = t & 3;
        int qn = min(q0 + row, NQ - 1);
        *(uint4*)&Qs[row * 40 + c * 8] =
            *(const uint4*)&q[((size_t)qn * BS + b) * D + h * DH + c * 8];
    }
    float m_run[4], l_run[4];
    #pragma unroll
    for (int r = 0; r < 4; ++r) { m_run[r] = -1e30f; l_run[r] = 0.f; }
    f32x4 oacc[2];
    oacc[0] = (f32x4){0.f, 0.f, 0.f, 0.f};
    oacc[1] = (f32x4){0.f, 0.f, 0.f, 0.f};
    __syncthreads();

    for (int k0 = 0; k0 < NQ; k0 += 64) {
        {
            int row = t >> 2, c = t & 3;
            int kn = min(k0 + row, NQ - 1);
            *(uint4*)&Ks[row * 40 + c * 8] =
                *(const uint4*)&k[((size_t)kn * BS + b) * D + h * DH + c * 8];
            uint4 vv = *(const uint4*)&v[((size_t)kn * BS + b) * D + h * DH + c * 8];
            ushort* pv = (ushort*)&vv;
            #pragma unroll
            for (int u = 0; u < 8; ++u) Vt[(c * 8 + u) * 72 + row] = pv[u];
        }
        __syncthreads();

        bf16x8 aq = *(const bf16x8*)&Qs[(w * 16 + l15) * 40 + kb * 8];
        f32x4 sacc[4];
        #pragma unroll
        for (int jj = 0; jj < 4; ++jj) {
            bf16x8 bk = *(const bf16x8*)&Ks[(jj * 16 + l15) * 40 + kb * 8];
            sacc[jj] = __builtin_amdgcn_mfma_f32_16x16x32_bf16(
                aq, bk, (f32x4){0.f, 0.f, 0.f, 0.f}, 0, 0, 0);
        }
        int kvalid = NQ - k0;
        #pragma unroll
        for (int jj = 0; jj < 4; ++jj) {
            #pragma unroll
            for (int r = 0; r < 4; ++r) sacc[jj][r] *= scale;
            if (jj * 16 + l15 >= kvalid) {
                #pragma unroll
                for (int r = 0; r < 4; ++r) sacc[jj][r] = -1e30f;
            }
        }
        float tm[4];
        #pragma unroll
        for (int r = 0; r < 4; ++r)
            tm[r] = fmaxf(fmaxf(sacc[0][r], sacc[1][r]), fmaxf(sacc[2][r], sacc[3][r]));
        #pragma unroll
        for (int msk = 1; msk <= 8; msk <<= 1)
            #pragma unroll
            for (int r = 0; r < 4; ++r) tm[r] = fmaxf(tm[r], __shfl_xor(tm[r], msk));
        float scl[4], newm[4];
        #pragma unroll
        for (int r = 0; r < 4; ++r) {
            newm[r] = fmaxf(m_run[r], tm[r]);
            scl[r] = __expf(m_run[r] - newm[r]);
            m_run[r] = newm[r];
        }
        float ps[4] = {0.f, 0.f, 0.f, 0.f};
        #pragma unroll
        for (int jj = 0; jj < 4; ++jj) {
            #pragma unroll
            for (int r = 0; r < 4; ++r) {
                float p = __expf(sacc[jj][r] - newm[r]);
                ps[r] += p;
                Pw[w * 1152 + (kb * 4 + r) * 72 + jj * 16 + l15] = f2bf(p);
            }
        }
        #pragma unroll
        for (int msk = 1; msk <= 8; msk <<= 1)
            #pragma unroll
            for (int r = 0; r < 4; ++r) ps[r] += __shfl_xor(ps[r], msk);
        #pragma unroll
        for (int r = 0; r < 4; ++r) l_run[r] = l_run[r] * scl[r] + ps[r];
        #pragma unroll
        for (int df = 0; df < 2; ++df)
            #pragma unroll
            for (int r = 0; r < 4; ++r) oacc[df][r] *= scl[r];
        #pragma unroll
        for (int hf = 0; hf < 2; ++hf) {
            bf16x8 pa = *(const bf16x8*)&Pw[w * 1152 + l15 * 72 + hf * 32 + kb * 8];
            #pragma unroll
            for (int df = 0; df < 2; ++df) {
                bf16x8 vb = *(const bf16x8*)&Vt[(df * 16 + l15) * 72 + hf * 32 + kb * 8];
                oacc[df] = __builtin_amdgcn_mfma_f32_16x16x32_bf16(pa, vb, oacc[df], 0, 0, 0);
            }
        }
        __syncthreads();
    }
    #pragma unroll
    for (int df = 0; df < 2; ++df) {
        #pragma unroll
        for (int r = 0; r < 4; ++r) {
            int qg = q0 + w * 16 + kb * 4 + r;
            if (qg < NQ)
                o[((size_t)qg * BS + b) * D + h * DH + df * 16 + l15] =
                    f2bf(oacc[df][r] / l_run[r]);
        }
    }
}

// ---------------- out = LayerNorm(x + y); MODE 0: f32; 1: +bf16; 2: +bf16(ln+pos) ----------------
template<int MODE>
__global__ void add_ln_kernel(const float* __restrict__ x, const float* __restrict__ y,
                              const float* __restrict__ g, const float* __restrict__ bt,
                              float* __restrict__ outf, ushort* __restrict__ outb,
                              const float* __restrict__ pos) {
    int m = blockIdx.x, t = threadIdx.x;
    __shared__ float red[8];
    float v = x[m * D + t] + y[m * D + t];
    int lane = t & 63, wid = t >> 6;
    float s = v;
    for (int off = 32; off; off >>= 1) s += __shfl_down(s, off);
    if (lane == 0) red[wid] = s;
    __syncthreads();
    if (t == 0) red[4] = (red[0] + red[1] + red[2] + red[3]) * (1.f / D);
    __syncthreads();
    float mu = red[4];
    float d = v - mu;
    float s2 = d * d;
    __syncthreads();
    for (int off = 32; off; off >>= 1) s2 += __shfl_down(s2, off);
    if (lane == 0) red[wid] = s2;
    __syncthreads();
    if (t == 0) red[5] = rsqrtf((red[0] + red[1] + red[2] + red[3]) * (1.f / D) + 1e-5f);
    __syncthreads();
    float res = d * red[5] * g[t] + bt[t];
    outf[m * D + t] = res;
    if (MODE == 1) outb[m * D + t] = f2bf(res);
    if (MODE == 2) outb[m * D + t] = f2bf(res + pos[m * D + t]);
}

// ---------------- deformable sampling: 2-phase (precompute addr/weights, then gather) ----------------
__global__ __launch_bounds__(256, 8)
void deform_kernel(const ushort* __restrict__ value, const float* __restrict__ offs,
                   const float* __restrict__ aw, const float* __restrict__ refp,
                   const int* __restrict__ shapes, const int* __restrict__ lsi,
                   ushort* __restrict__ outb) {
    int n = blockIdx.x, b = blockIdx.y;
    int t = threadIdx.x;
    int m = n * BS + b;
    __shared__ float awn[NH * 16];
    __shared__ int4  sadr[128];
    __shared__ float4 swt[128];
    if (t < NH) {
        const float* p = aw + (size_t)m * 128 + t * 16;
        float mx = p[0];
        #pragma unroll
        for (int jj = 1; jj < 16; ++jj) mx = fmaxf(mx, p[jj]);
        float e[16], s = 0.f;
        #pragma unroll
        for (int jj = 0; jj < 16; ++jj) { e[jj] = __expf(p[jj] - mx); s += e[jj]; }
        float inv = 1.f / s;
        #pragma unroll
        for (int jj = 0; jj < 16; ++jj) awn[t * 16 + jj] = e[jj] * inv;
    }
    __syncthreads();
    if (t < 128) {
        int h = t >> 4, l = (t >> 2) & 3, p = t & 3;
        int Hl = shapes[l * 2], Wl = shapes[l * 2 + 1], s = lsi[l];
        float Wf = (float)Wl, Hf = (float)Hl;
        float rx = refp[(m * NL + l) * 2 + 0];
        float ry = refp[(m * NL + l) * 2 + 1];
        int oc = ((h * NL + l) * NP + p) * 2;
        float ox = offs[m * 256 + oc];
        float oy = offs[m * 256 + oc + 1];
        float ww = awn[h * 16 + l * NP + p];
        float x = (rx + ox / Wf) * Wf - 0.5f;
        float y = (ry + oy / Hf) * Hf - 0.5f;
        float x0 = floorf(x), y0 = floorf(y);
        float lx = x - x0, ly = y - y0;
        int xi = (int)x0, yi = (int)y0;
        int4 a4; float4 w4;
        int* ap = (int*)&a4; float* wp = (float*)&w4;
        #pragma unroll
        for (int cy = 0; cy < 2; ++cy) {
            #pragma unroll
            for (int cx = 0; cx < 2; ++cx) {
                int xx = xi + cx, yy = yi + cy;
                bool valid = (xx >= 0 && xx < Wl && yy >= 0 && yy < Hl);
                float cw = (cx ? lx : 1.f - lx) * (cy ? ly : 1.f - ly);
                ap[cy * 2 + cx] = valid ? (int)(((size_t)(s + yy * Wl + xx) * BS + b) * D + h * DH) : 0;
                wp[cy * 2 + cx] = valid ? ww * cw : 0.f;
            }
        }
        sadr[t] = a4;
        swt[t] = w4;
    }
    __syncthreads();
    int h = t >> 5, dh = t & 31;
    float acc = 0.f;
    #pragma unroll
    for (int i = 0; i < 16; ++i) {
        int4 a4 = sadr[h * 16 + i];
        float4 w4 = swt[h * 16 + i];
        acc += w4.x * bf2f(value[a4.x + dh]);
        acc += w4.y * bf2f(value[a4.y + dh]);
        acc += w4.z * bf2f(value[a4.z + dh]);
        acc += w4.w * bf2f(value[a4.w + dh]);
    }
    outb[m * D + h * DH + dh] = f2bf(acc);
}

extern "C" void kernel_launch(void* const* d_in, const int* in_sizes, int n_in,
                              void* d_out, int out_size, void* d_ws, size_t ws_size,
                              hipStream_t stream) {
    const float* tgt    = (const float*)d_in[0];
    const float* pos    = (const float*)d_in[1];
    const float* refp   = (const float*)d_in[2];
    const float* memory = (const float*)d_in[3];
    const int*   shapes = (const int*)d_in[4];
    const int*   lsi    = (const int*)d_in[5];
    const float* sa_wq = (const float*)d_in[6],  *sa_bq = (const float*)d_in[7];
    const float* sa_wk = (const float*)d_in[8],  *sa_bk = (const float*)d_in[9];
    const float* sa_wv = (const float*)d_in[10], *sa_bv = (const float*)d_in[11];
    const float* sa_wo = (const float*)d_in[12], *sa_bo = (const float*)d_in[13];
    const float* ln2_g = (const float*)d_in[14], *ln2_b = (const float*)d_in[15];
    const float* ca_wval = (const float*)d_in[16], *ca_bval = (const float*)d_in[17];
    const float* ca_woff = (const float*)d_in[18], *ca_boff = (const float*)d_in[19];
    const float* ca_wattn = (const float*)d_in[20], *ca_battn = (const float*)d_in[21];
    const float* ca_wout = (const float*)d_in[22], *ca_bout = (const float*)d_in[23];
    const float* ln1_g = (const float*)d_in[24], *ln1_b = (const float*)d_in[25];
    const float* ffn_w1 = (const float*)d_in[26], *ffn_b1 = (const float*)d_in[27];
    const float* ffn_w2 = (const float*)d_in[28], *ffn_b2 = (const float*)d_in[29];
    const float* ln3_g = (const float*)d_in[30], *ln3_b = (const float*)d_in[31];
    float* out = (float*)d_out;

    // ---- workspace: bf16 area then f32 area ----
    ushort* wt = (ushort*)d_ws;
    ushort* wtq   = wt + 0;
    ushort* wtk   = wt + 65536;
    ushort* wtv   = wt + 131072;
    ushort* wto   = wt + 196608;
    ushort* wtval = wt + 262144;
    ushort* wtoff = wt + 327680;
    ushort* wtattn= wt + 393216;
    ushort* wtout = wt + 425984;
    ushort* wtf1  = wt + 491520;
    ushort* wtf2  = wt + 753664;
    const size_t MD = (size_t)MROWS * D;
    ushort* x_bf   = wt + 1015808;
    ushort* tgt_bf = x_bf + MD;
    ushort* q_bf   = tgt_bf + MD;
    ushort* k_bf   = q_bf + MD;
    ushort* v_bf   = k_bf + MD;
    ushort* o_bf   = v_bf + MD;
    ushort* value_bf = o_bf + MD;
    ushort* query_bf = x_bf;
    ushort* samp_bf  = tgt_bf;
    ushort* tgt2_bf  = q_bf;
    ushort* hbuf_bf  = value_bf;
    float* fws = (float*)(value_bf + (size_t)LV * BS * D);
    float* xo   = fws;
    float* tgt1 = xo + MD;
    float* tgt2 = tgt1 + MD;
    float* offs = tgt2 + MD;
    float* aw   = offs + MD;
    (void)ws_size; (void)in_sizes; (void)n_in; (void)out_size;

    dim3 b256(256);
    Job jz = {};
    auto mkb = [](const ushort* Xb, const ushort* Wt, const float* bias,
                  float* Yf, ushort* Yb, int M, int K, int N, int relu) {
        Job j; j.Xb = Xb; j.Xf = nullptr; j.Wt = Wt; j.bias = bias;
        j.Yf = Yf; j.Yb = Yb; j.M = M; j.K = K; j.N = N; j.relu = relu; return j;
    };

    // 1. weights
    wt_transpose_kernel<<<dim3(256, 1, 10), b256, 0, stream>>>(
        sa_wq, sa_wk, sa_wv, sa_wo, ca_wval, ca_woff, ca_wattn, ca_wout, ffn_w1, ffn_w2,
        wtq, wtk, wtv, wto, wtval, wtoff, wtattn, wtout, wtf1, wtf2);
    // 2. activations -> bf16
    prep_x_kernel<<<dim3(MD / 4 / 256), b256, 0, stream>>>(tgt, pos, x_bf, tgt_bf);
    // 3. q,k,v projections (batched)
    gemm_bf_kernel<<<dim3(4, 57, 3), b256, 0, stream>>>(
        mkb(x_bf, wtq, sa_bq, nullptr, q_bf, MROWS, D, D, 0),
        mkb(x_bf, wtk, sa_bk, nullptr, k_bf, MROWS, D, D, 0),
        mkb(tgt_bf, wtv, sa_bv, nullptr, v_bf, MROWS, D, D, 0));
    // 4. self attention
    sa_mfma_kernel<<<dim3(15, NH, BS), b256, 0, stream>>>(q_bf, k_bf, v_bf, o_bf);
    // 5. o-projection
    gemm_bf_kernel<<<dim3(4, 57, 1), b256, 0, stream>>>(
        mkb(o_bf, wto, sa_bo, xo, nullptr, MROWS, D, D, 0), jz, jz);
    // 6. LN2 (+ query_bf = bf(ln + pos))
    add_ln_kernel<2><<<dim3(MROWS), b256, 0, stream>>>(tgt, xo, ln2_g, ln2_b, tgt1, query_bf, pos);
    // 7. value projection
    gemm_wide_kernel<<<dim3((LV * BS + 63) / 64), dim3(512), 0, stream>>>(
        memory, wtval, ca_bval, value_bf, LV * BS);
    // 8. offsets + attention weights (batched; softmax fused into deform)
    gemm_bf_kernel<<<dim3(4, 57, 2), b256, 0, stream>>>(
        mkb(query_bf, wtoff, ca_boff, offs, nullptr, MROWS, D, 256, 0),
        mkb(query_bf, wtattn, ca_battn, aw, nullptr, MROWS, D, 128, 0), jz);
    // 9. deformable sampling (softmax inside, 2-phase)
    deform_kernel<<<dim3(NQ, BS), b256, 0, stream>>>(value_bf, offs, aw, refp, shapes, lsi, samp_bf);
    // 10. out-projection
    gemm_bf_kernel<<<dim3(4, 57, 1), b256, 0, stream>>>(
        mkb(samp_bf, wtout, ca_bout, xo, nullptr, MROWS, D, D, 0), jz, jz);
    // 11. LN1 (+ tgt2_bf)
    add_ln_kernel<1><<<dim3(MROWS), b256, 0, stream>>>(tgt1, xo, ln1_g, ln1_b, tgt2, tgt2_bf, nullptr);
    // 12. FFN1 (relu, bf16 out)
    gemm_bf_kernel<<<dim3(16, 57, 1), b256, 0, stream>>>(
        mkb(tgt2_bf, wtf1, ffn_b1, nullptr, hbuf_bf, MROWS, D, DFF, 1), jz, jz);
    // 13. FFN2
    gemm_bf_kernel<<<dim3(4, 57, 1), b256, 0, stream>>>(
        mkb(hbuf_bf, wtf2, ffn_b2, xo, nullptr, MROWS, DFF, D, 0), jz, jz);
    // 14. LN3 -> out
    add_ln_kernel<0><<<dim3(MROWS), b256, 0, stream>>>(tgt2, xo, ln3_g, ln3_b, out, nullptr, nullptr);
}

// Round 14
// 203.024 us; speedup vs baseline: 1.2245x; 1.0623x over previous
//
#include <hip/hip_runtime.h>

#define D    256
#define NH   8
#define DH   32
#define NL   4
#define NP   4
#define DFF  1024
#define NQ   900
#define BS   4
#define LV   13294
#define MROWS (NQ*BS)   // 3600

typedef short bf16x8 __attribute__((ext_vector_type(8)));
typedef float f32x4  __attribute__((ext_vector_type(4)));

__device__ inline ushort f2bf(float f) {
    unsigned u = __float_as_uint(f);
    unsigned r = (u + 0x7fffu + ((u >> 16) & 1u)) >> 16;
    return (ushort)r;
}
__device__ inline float bf2f(ushort u) { return __uint_as_float(((unsigned)u) << 16); }

// ---------------- prep: x_bf = bf(tgt+pos), tgt_bf = bf(tgt) ----------------
__global__ void prep_x_kernel(const float* __restrict__ tgt, const float* __restrict__ pos,
                              ushort* __restrict__ x_bf, ushort* __restrict__ tgt_bf) {
    int i = blockIdx.x * blockDim.x + threadIdx.x;
    float4 a = *(const float4*)&tgt[(size_t)i * 4];
    float4 p = *(const float4*)&pos[(size_t)i * 4];
    ushort4 xo, to;
    to.x = f2bf(a.x); to.y = f2bf(a.y); to.z = f2bf(a.z); to.w = f2bf(a.w);
    xo.x = f2bf(a.x + p.x); xo.y = f2bf(a.y + p.y); xo.z = f2bf(a.z + p.z); xo.w = f2bf(a.w + p.w);
    *(ushort4*)&x_bf[(size_t)i * 4] = xo;
    *(ushort4*)&tgt_bf[(size_t)i * 4] = to;
}

// ---------------- weight transpose+convert: W[K][N] f32 -> Wt[N][K] bf16 ----------------
__global__ void wt_transpose_kernel(
    const float* w0, const float* w1, const float* w2, const float* w3, const float* w4,
    const float* w5, const float* w6, const float* w7, const float* w8, const float* w9,
    ushort* o0, ushort* o1, ushort* o2, ushort* o3, ushort* o4,
    ushort* o5, ushort* o6, ushort* o7, ushort* o8, ushort* o9) {
    __shared__ float Ts[32][33];
    int z = blockIdx.z;
    const float* src; ushort* dst; int K, N;
    switch (z) {
        case 0: src = w0; dst = o0; K = 256;  N = 256;  break;
        case 1: src = w1; dst = o1; K = 256;  N = 256;  break;
        case 2: src = w2; dst = o2; K = 256;  N = 256;  break;
        case 3: src = w3; dst = o3; K = 256;  N = 256;  break;
        case 4: src = w4; dst = o4; K = 256;  N = 256;  break;
        case 5: src = w5; dst = o5; K = 256;  N = 256;  break;
        case 6: src = w6; dst = o6; K = 256;  N = 128;  break;
        case 7: src = w7; dst = o7; K = 256;  N = 256;  break;
        case 8: src = w8; dst = o8; K = 256;  N = 1024; break;
        default:src = w9; dst = o9; K = 1024; N = 256;  break;
    }
    int tiles_n = N >> 5;
    int tile = blockIdx.x;
    int tx = tile % tiles_n, ty = tile / tiles_n;
    if (ty >= (K >> 5)) return;
    int n0 = tx * 32, k0 = ty * 32;
    int t = threadIdx.x;
    #pragma unroll
    for (int i = 0; i < 4; ++i) {
        int e = t + i * 256; int r = e >> 5, c = e & 31;
        Ts[r][c] = src[(size_t)(k0 + r) * N + n0 + c];
    }
    __syncthreads();
    #pragma unroll
    for (int i = 0; i < 4; ++i) {
        int e = t + i * 256; int r = e >> 5, c = e & 31;
        dst[(size_t)(n0 + r) * K + k0 + c] = f2bf(Ts[c][r]);
    }
}

// ---------------- bf16 MFMA GEMM: Y[M,N] = X[M,K] @ Wt[N,K]^T + bias ----------------
struct Job {
    const ushort* Xb;
    const float*  Xf;
    const ushort* Wt;
    const float*  bias;
    float*  Yf;
    ushort* Yb;
    int M, K, N, relu;
};

__global__ __launch_bounds__(256, 3)
void gemm_bf_kernel(Job j0, Job j1, Job j2) {
    Job j = (blockIdx.z == 0) ? j0 : (blockIdx.z == 1 ? j1 : j2);
    const int row0 = blockIdx.y * 64, col0 = blockIdx.x * 64;
    if (row0 >= j.M || col0 >= j.N) return;
    __shared__ ushort As[64 * 72];
    __shared__ ushort Bs[64 * 72];
    const int t = threadIdx.x, w = t >> 6, lane = t & 63;
    const int wr = w >> 1, wc = w & 1, l15 = lane & 15, kb = lane >> 4;

    f32x4 acc[2][2];
    #pragma unroll
    for (int i = 0; i < 2; ++i)
        #pragma unroll
        for (int jj = 0; jj < 2; ++jj) acc[i][jj] = (f32x4){0.f, 0.f, 0.f, 0.f};

    uint4 ra0, ra1, rb0, rb1;
    float4 rf0, rf1, rf2, rf3;

    auto gload = [&](int k0) {
        if (j.Xb) {
            {
                int e = t;              int row = e >> 3, c = e & 7;
                int gr = row0 + row; if (gr >= j.M) gr = j.M - 1;
                ra0 = *(const uint4*)&j.Xb[(size_t)gr * j.K + k0 + c * 8];
            }
            {
                int e = t + 256;        int row = e >> 3, c = e & 7;
                int gr = row0 + row; if (gr >= j.M) gr = j.M - 1;
                ra1 = *(const uint4*)&j.Xb[(size_t)gr * j.K + k0 + c * 8];
            }
        } else {
            {
                int e = t;              int row = e >> 4, q = e & 15;
                int gr = row0 + row; if (gr >= j.M) gr = j.M - 1;
                rf0 = *(const float4*)&j.Xf[(size_t)gr * j.K + k0 + q * 4];
            }
            {
                int e = t + 256;        int row = e >> 4, q = e & 15;
                int gr = row0 + row; if (gr >= j.M) gr = j.M - 1;
                rf1 = *(const float4*)&j.Xf[(size_t)gr * j.K + k0 + q * 4];
            }
            {
                int e = t + 512;        int row = e >> 4, q = e & 15;
                int gr = row0 + row; if (gr >= j.M) gr = j.M - 1;
                rf2 = *(const float4*)&j.Xf[(size_t)gr * j.K + k0 + q * 4];
            }
            {
                int e = t + 768;        int row = e >> 4, q = e & 15;
                int gr = row0 + row; if (gr >= j.M) gr = j.M - 1;
                rf3 = *(const float4*)&j.Xf[(size_t)gr * j.K + k0 + q * 4];
            }
        }
        {
            int e = t;                  int row = e >> 3, c = e & 7;
            rb0 = *(const uint4*)&j.Wt[(size_t)(col0 + row) * j.K + k0 + c * 8];
        }
        {
            int e = t + 256;            int row = e >> 3, c = e & 7;
            rb1 = *(const uint4*)&j.Wt[(size_t)(col0 + row) * j.K + k0 + c * 8];
        }
    };
    auto cvt4 = [](float4 f) {
        ushort4 pk;
        pk.x = f2bf(f.x); pk.y = f2bf(f.y); pk.z = f2bf(f.z); pk.w = f2bf(f.w);
        return pk;
    };
    auto lwrite = [&]() {
        if (j.Xb) {
            { int e = t;       int row = e >> 3, c = e & 7; *(uint4*)&As[row * 72 + c * 8] = ra0; }
            { int e = t + 256; int row = e >> 3, c = e & 7; *(uint4*)&As[row * 72 + c * 8] = ra1; }
        } else {
            { int e = t;       int row = e >> 4, q = e & 15; *(ushort4*)&As[row * 72 + q * 4] = cvt4(rf0); }
            { int e = t + 256; int row = e >> 4, q = e & 15; *(ushort4*)&As[row * 72 + q * 4] = cvt4(rf1); }
            { int e = t + 512; int row = e >> 4, q = e & 15; *(ushort4*)&As[row * 72 + q * 4] = cvt4(rf2); }
            { int e = t + 768; int row = e >> 4, q = e & 15; *(ushort4*)&As[row * 72 + q * 4] = cvt4(rf3); }
        }
        { int e = t;       int row = e >> 3, c = e & 7; *(uint4*)&Bs[row * 72 + c * 8] = rb0; }
        { int e = t + 256; int row = e >> 3, c = e & 7; *(uint4*)&Bs[row * 72 + c * 8] = rb1; }
    };
    auto compute = [&]() {
        bf16x8 a[2][2], b[2][2];
        #pragma unroll
        for (int i = 0; i < 2; ++i)
            #pragma unroll
            for (int kh = 0; kh < 2; ++kh)
                a[i][kh] = *(const bf16x8*)&As[(wr * 32 + i * 16 + l15) * 72 + (kh * 4 + kb) * 8];
        #pragma unroll
        for (int jj = 0; jj < 2; ++jj)
            #pragma unroll
            for (int kh = 0; kh < 2; ++kh)
                b[jj][kh] = *(const bf16x8*)&Bs[(wc * 32 + jj * 16 + l15) * 72 + (kh * 4 + kb) * 8];
        #pragma unroll
        for (int kh = 0; kh < 2; ++kh)
            #pragma unroll
            for (int i = 0; i < 2; ++i)
                #pragma unroll
                for (int jj = 0; jj < 2; ++jj)
                    acc[i][jj] = __builtin_amdgcn_mfma_f32_16x16x32_bf16(
                        a[i][kh], b[jj][kh], acc[i][jj], 0, 0, 0);
    };

    gload(0);
    lwrite();
    __syncthreads();
    const int nt = j.K >> 6;
    for (int tt = 0; tt < nt; ++tt) {
        if (tt + 1 < nt) gload((tt + 1) << 6);
        compute();
        __syncthreads();
        if (tt + 1 < nt) { lwrite(); __syncthreads(); }
    }

    if (j.Yb) {
        #pragma unroll
        for (int i = 0; i < 2; ++i) {
            #pragma unroll
            for (int jj = 0; jj < 2; ++jj) {
                int lcol = wc * 32 + jj * 16 + l15;
                float bv = j.bias[col0 + lcol];
                #pragma unroll
                for (int r = 0; r < 4; ++r) {
                    int lrow = wr * 32 + i * 16 + kb * 4 + r;
                    float vv = acc[i][jj][r] + bv;
                    if (j.relu) vv = fmaxf(vv, 0.f);
                    As[lrow * 64 + lcol] = f2bf(vv);
                }
            }
        }
        __syncthreads();
        #pragma unroll
        for (int it = 0; it < 2; ++it) {
            int idx = t + it * 256;
            int lrow = idx >> 3, c = idx & 7;
            int grow = row0 + lrow;
            if (grow < j.M)
                *(uint4*)&j.Yb[(size_t)grow * j.N + col0 + c * 8] =
                    *(const uint4*)&As[lrow * 64 + c * 8];
        }
    } else {
        #pragma unroll
        for (int i = 0; i < 2; ++i) {
            #pragma unroll
            for (int jj = 0; jj < 2; ++jj) {
                int gcol = col0 + wc * 32 + jj * 16 + l15;
                float bv = j.bias[gcol];
                #pragma unroll
                for (int r = 0; r < 4; ++r) {
                    int grow = row0 + wr * 32 + i * 16 + kb * 4 + r;
                    if (grow < j.M) {
                        float vv = acc[i][jj][r] + bv;
                        if (j.relu) vv = fmaxf(vv, 0.f);
                        j.Yf[(size_t)grow * j.N + gcol] = vv;
                    }
                }
            }
        }
    }
}

// ---------------- wide GEMM for value projection: Y[M,256] = X[M,256](f32) @ Wt^T ----------------
// 128-row x 256-col tile, 512 threads (8 waves, 2x4 of 64x64), 416 blocks.
__global__ __launch_bounds__(512, 2)
void gemm_wide_kernel(const float* __restrict__ Xf, const ushort* __restrict__ Wt,
                      const float* __restrict__ bias, ushort* __restrict__ Yb, int M) {
    __shared__ ushort As[128 * 72];
    __shared__ ushort Bs[256 * 72];
    const int t = threadIdx.x, w = t >> 6, lane = t & 63;
    const int wr = w >> 2, wc = w & 3, l15 = lane & 15, kb = lane >> 4;
    const int row0 = blockIdx.x * 128;

    f32x4 acc[4][4];
    #pragma unroll
    for (int i = 0; i < 4; ++i)
        #pragma unroll
        for (int jj = 0; jj < 4; ++jj) acc[i][jj] = (f32x4){0.f, 0.f, 0.f, 0.f};

    float4 rf[4];
    uint4 rb[4];

    auto gload = [&](int k0) {
        #pragma unroll
        for (int i = 0; i < 4; ++i) {
            int e = t + i * 512; int row = e >> 4, q = e & 15;
            int gr = row0 + row; if (gr >= M) gr = M - 1;
            rf[i] = *(const float4*)&Xf[(size_t)gr * 256 + k0 + q * 4];
        }
        #pragma unroll
        for (int i = 0; i < 4; ++i) {
            int e = t + i * 512; int row = e >> 3, c = e & 7;
            rb[i] = *(const uint4*)&Wt[(size_t)row * 256 + k0 + c * 8];
        }
    };
    auto cvt4 = [](float4 f) {
        ushort4 pk;
        pk.x = f2bf(f.x); pk.y = f2bf(f.y); pk.z = f2bf(f.z); pk.w = f2bf(f.w);
        return pk;
    };
    auto lwrite = [&]() {
        #pragma unroll
        for (int i = 0; i < 4; ++i) {
            int e = t + i * 512; int row = e >> 4, q = e & 15;
            *(ushort4*)&As[row * 72 + q * 4] = cvt4(rf[i]);
        }
        #pragma unroll
        for (int i = 0; i < 4; ++i) {
            int e = t + i * 512; int row = e >> 3, c = e & 7;
            *(uint4*)&Bs[row * 72 + c * 8] = rb[i];
        }
    };
    auto compute = [&]() {
        bf16x8 a[4][2], b[4][2];
        #pragma unroll
        for (int i = 0; i < 4; ++i)
            #pragma unroll
            for (int kh = 0; kh < 2; ++kh)
                a[i][kh] = *(const bf16x8*)&As[(wr * 64 + i * 16 + l15) * 72 + (kh * 4 + kb) * 8];
        #pragma unroll
        for (int jj = 0; jj < 4; ++jj)
            #pragma unroll
            for (int kh = 0; kh < 2; ++kh)
                b[jj][kh] = *(const bf16x8*)&Bs[(wc * 64 + jj * 16 + l15) * 72 + (kh * 4 + kb) * 8];
        #pragma unroll
        for (int kh = 0; kh < 2; ++kh)
            #pragma unroll
            for (int i = 0; i < 4; ++i)
                #pragma unroll
                for (int jj = 0; jj < 4; ++jj)
                    acc[i][jj] = __builtin_amdgcn_mfma_f32_16x16x32_bf16(
                        a[i][kh], b[jj][kh], acc[i][jj], 0, 0, 0);
    };

    gload(0);
    lwrite();
    __syncthreads();
    #pragma unroll
    for (int tt = 0; tt < 4; ++tt) {
        if (tt + 1 < 4) gload((tt + 1) << 6);
        compute();
        __syncthreads();
        if (tt + 1 < 4) { lwrite(); __syncthreads(); }
    }

    // epilogue: two 64-row halves staged through Bs (32 KB each), coalesced stores
    ushort* obuf = Bs;
    #pragma unroll
    for (int half = 0; half < 2; ++half) {
        if (wr == half) {
            #pragma unroll
            for (int i = 0; i < 4; ++i) {
                #pragma unroll
                for (int jj = 0; jj < 4; ++jj) {
                    int lcol = wc * 64 + jj * 16 + l15;
                    float bv = bias[lcol];
                    #pragma unroll
                    for (int r = 0; r < 4; ++r) {
                        int lrow = i * 16 + kb * 4 + r;   // 0..63
                        obuf[lrow * 256 + lcol] = f2bf(acc[i][jj][r] + bv);
                    }
                }
            }
        }
        __syncthreads();
        #pragma unroll
        for (int it = 0; it < 4; ++it) {
            int idx = t + it * 512;           // 2048 uint4 = 64 rows x 32
            int lrow = idx >> 5, c = idx & 31;
            int grow = row0 + half * 64 + lrow;
            if (grow < M)
                *(uint4*)&Yb[(size_t)grow * 256 + c * 8] =
                    *(const uint4*)&obuf[lrow * 256 + c * 8];
        }
        __syncthreads();
    }
}

// ---------------- MFMA flash self-attention (bf16 in/out) ----------------
__global__ __launch_bounds__(256, 2)
void sa_mfma_kernel(const ushort* __restrict__ q, const ushort* __restrict__ k,
                    const ushort* __restrict__ v, ushort* __restrict__ o) {
    __shared__ ushort Qs[64 * 40];
    __shared__ ushort Ks[64 * 40];
    __shared__ ushort Vt[32 * 72];
    __shared__ ushort Pw[4 * 16 * 72];
    const int qt = blockIdx.x, h = blockIdx.y, b = blockIdx.z;
    const int q0 = qt * 64, t = threadIdx.x;
    const int w = t >> 6, lane = t & 63;
    const int l15 = lane & 15, kb = lane >> 4;
    const float scale = 0.17677669529663687f;

    {
        int row = t >> 2, c = t & 3;
        int qn = min(q0 + row, NQ - 1);
        *(uint4*)&Qs[row * 40 + c * 8] =
            *(const uint4*)&q[((size_t)qn * BS + b) * D + h * DH + c * 8];
    }
    float m_run[4], l_run[4];
    #pragma unroll
    for (int r = 0; r < 4; ++r) { m_run[r] = -1e30f; l_run[r] = 0.f; }
    f32x4 oacc[2];
    oacc[0] = (f32x4){0.f, 0.f, 0.f, 0.f};
    oacc[1] = (f32x4){0.f, 0.f, 0.f, 0.f};
    __syncthreads();

    for (int k0 = 0; k0 < NQ; k0 += 64) {
        {
            int row = t >> 2, c = t & 3;
            int kn = min(k0 + row, NQ - 1);
            *(uint4*)&Ks[row * 40 + c * 8] =
                *(const uint4*)&k[((size_t)kn * BS + b) * D + h * DH + c * 8];
            uint4 vv = *(const uint4*)&v[((size_t)kn * BS + b) * D + h * DH + c * 8];
            ushort* pv = (ushort*)&vv;
            #pragma unroll
            for (int u = 0; u < 8; ++u) Vt[(c * 8 + u) * 72 + row] = pv[u];
        }
        __syncthreads();

        bf16x8 aq = *(const bf16x8*)&Qs[(w * 16 + l15) * 40 + kb * 8];
        f32x4 sacc[4];
        #pragma unroll
        for (int jj = 0; jj < 4; ++jj) {
            bf16x8 bk = *(const bf16x8*)&Ks[(jj * 16 + l15) * 40 + kb * 8];
            sacc[jj] = __builtin_amdgcn_mfma_f32_16x16x32_bf16(
                aq, bk, (f32x4){0.f, 0.f, 0.f, 0.f}, 0, 0, 0);
        }
        int kvalid = NQ - k0;
        #pragma unroll
        for (int jj = 0; jj < 4; ++jj) {
            #pragma unroll
            for (int r = 0; r < 4; ++r) sacc[jj][r] *= scale;
            if (jj * 16 + l15 >= kvalid) {
                #pragma unroll
                for (int r = 0; r < 4; ++r) sacc[jj][r] = -1e30f;
            }
        }
        float tm[4];
        #pragma unroll
        for (int r = 0; r < 4; ++r)
            tm[r] = fmaxf(fmaxf(sacc[0][r], sacc[1][r]), fmaxf(sacc[2][r], sacc[3][r]));
        #pragma unroll
        for (int msk = 1; msk <= 8; msk <<= 1)
            #pragma unroll
            for (int r = 0; r < 4; ++r) tm[r] = fmaxf(tm[r], __shfl_xor(tm[r], msk));
        float scl[4], newm[4];
        #pragma unroll
        for (int r = 0; r < 4; ++r) {
            newm[r] = fmaxf(m_run[r], tm[r]);
            scl[r] = __expf(m_run[r] - newm[r]);
            m_run[r] = newm[r];
        }
        float ps[4] = {0.f, 0.f, 0.f, 0.f};
        #pragma unroll
        for (int jj = 0; jj < 4; ++jj) {
            #pragma unroll
            for (int r = 0; r < 4; ++r) {
                float p = __expf(sacc[jj][r] - newm[r]);
                ps[r] += p;
                Pw[w * 1152 + (kb * 4 + r) * 72 + jj * 16 + l15] = f2bf(p);
            }
        }
        #pragma unroll
        for (int msk = 1; msk <= 8; msk <<= 1)
            #pragma unroll
            for (int r = 0; r < 4; ++r) ps[r] += __shfl_xor(ps[r], msk);
        #pragma unroll
        for (int r = 0; r < 4; ++r) l_run[r] = l_run[r] * scl[r] + ps[r];
        #pragma unroll
        for (int df = 0; df < 2; ++df)
            #pragma unroll
            for (int r = 0; r < 4; ++r) oacc[df][r] *= scl[r];
        #pragma unroll
        for (int hf = 0; hf < 2; ++hf) {
            bf16x8 pa = *(const bf16x8*)&Pw[w * 1152 + l15 * 72 + hf * 32 + kb * 8];
            #pragma unroll
            for (int df = 0; df < 2; ++df) {
                bf16x8 vb = *(const bf16x8*)&Vt[(df * 16 + l15) * 72 + hf * 32 + kb * 8];
                oacc[df] = __builtin_amdgcn_mfma_f32_16x16x32_bf16(pa, vb, oacc[df], 0, 0, 0);
            }
        }
        __syncthreads();
    }
    #pragma unroll
    for (int df = 0; df < 2; ++df) {
        #pragma unroll
        for (int r = 0; r < 4; ++r) {
            int qg = q0 + w * 16 + kb * 4 + r;
            if (qg < NQ)
                o[((size_t)qg * BS + b) * D + h * DH + df * 16 + l15] =
                    f2bf(oacc[df][r] / l_run[r]);
        }
    }
}

// ---------------- out = LayerNorm(x + y); MODE 0: f32; 1: +bf16; 2: +bf16(ln+pos) ----------------
template<int MODE>
__global__ void add_ln_kernel(const float* __restrict__ x, const float* __restrict__ y,
                              const float* __restrict__ g, const float* __restrict__ bt,
                              float* __restrict__ outf, ushort* __restrict__ outb,
                              const float* __restrict__ pos) {
    int m = blockIdx.x, t = threadIdx.x;
    __shared__ float red[8];
    float v = x[m * D + t] + y[m * D + t];
    int lane = t & 63, wid = t >> 6;
    float s = v;
    for (int off = 32; off; off >>= 1) s += __shfl_down(s, off);
    if (lane == 0) red[wid] = s;
    __syncthreads();
    if (t == 0) red[4] = (red[0] + red[1] + red[2] + red[3]) * (1.f / D);
    __syncthreads();
    float mu = red[4];
    float d = v - mu;
    float s2 = d * d;
    __syncthreads();
    for (int off = 32; off; off >>= 1) s2 += __shfl_down(s2, off);
    if (lane == 0) red[wid] = s2;
    __syncthreads();
    if (t == 0) red[5] = rsqrtf((red[0] + red[1] + red[2] + red[3]) * (1.f / D) + 1e-5f);
    __syncthreads();
    float res = d * red[5] * g[t] + bt[t];
    outf[m * D + t] = res;
    if (MODE == 1) outb[m * D + t] = f2bf(res);
    if (MODE == 2) outb[m * D + t] = f2bf(res + pos[m * D + t]);
}

// ---------------- deformable sampling: 2-phase (precompute addr/weights, then gather) ----------------
__global__ __launch_bounds__(256, 8)
void deform_kernel(const ushort* __restrict__ value, const float* __restrict__ offs,
                   const float* __restrict__ aw, const float* __restrict__ refp,
                   const int* __restrict__ shapes, const int* __restrict__ lsi,
                   ushort* __restrict__ outb) {
    int n = blockIdx.x, b = blockIdx.y;
    int t = threadIdx.x;
    int m = n * BS + b;
    __shared__ float awn[NH * 16];
    __shared__ int4  sadr[128];
    __shared__ float4 swt[128];
    if (t < NH) {
        const float* p = aw + (size_t)m * 128 + t * 16;
        float mx = p[0];
        #pragma unroll
        for (int jj = 1; jj < 16; ++jj) mx = fmaxf(mx, p[jj]);
        float e[16], s = 0.f;
        #pragma unroll
        for (int jj = 0; jj < 16; ++jj) { e[jj] = __expf(p[jj] - mx); s += e[jj]; }
        float inv = 1.f / s;
        #pragma unroll
        for (int jj = 0; jj < 16; ++jj) awn[t * 16 + jj] = e[jj] * inv;
    }
    __syncthreads();
    if (t < 128) {
        int h = t >> 4, l = (t >> 2) & 3, p = t & 3;
        int Hl = shapes[l * 2], Wl = shapes[l * 2 + 1], s = lsi[l];
        float Wf = (float)Wl, Hf = (float)Hl;
        float rx = refp[(m * NL + l) * 2 + 0];
        float ry = refp[(m * NL + l) * 2 + 1];
        int oc = ((h * NL + l) * NP + p) * 2;
        float ox = offs[m * 256 + oc];
        float oy = offs[m * 256 + oc + 1];
        float ww = awn[h * 16 + l * NP + p];
        float x = (rx + ox / Wf) * Wf - 0.5f;
        float y = (ry + oy / Hf) * Hf - 0.5f;
        float x0 = floorf(x), y0 = floorf(y);
        float lx = x - x0, ly = y - y0;
        int xi = (int)x0, yi = (int)y0;
        int4 a4; float4 w4;
        int* ap = (int*)&a4; float* wp = (float*)&w4;
        #pragma unroll
        for (int cy = 0; cy < 2; ++cy) {
            #pragma unroll
            for (int cx = 0; cx < 2; ++cx) {
                int xx = xi + cx, yy = yi + cy;
                bool valid = (xx >= 0 && xx < Wl && yy >= 0 && yy < Hl);
                float cw = (cx ? lx : 1.f - lx) * (cy ? ly : 1.f - ly);
                ap[cy * 2 + cx] = valid ? (int)(((size_t)(s + yy * Wl + xx) * BS + b) * D + h * DH) : 0;
                wp[cy * 2 + cx] = valid ? ww * cw : 0.f;
            }
        }
        sadr[t] = a4;
        swt[t] = w4;
    }
    __syncthreads();
    int h = t >> 5, dh = t & 31;
    float acc = 0.f;
    #pragma unroll
    for (int i = 0; i < 16; ++i) {
        int4 a4 = sadr[h * 16 + i];
        float4 w4 = swt[h * 16 + i];
        acc += w4.x * bf2f(value[a4.x + dh]);
        acc += w4.y * bf2f(value[a4.y + dh]);
        acc += w4.z * bf2f(value[a4.z + dh]);
        acc += w4.w * bf2f(value[a4.w + dh]);
    }
    outb[m * D + h * DH + dh] = f2bf(acc);
}

extern "C" void kernel_launch(void* const* d_in, const int* in_sizes, int n_in,
                              void* d_out, int out_size, void* d_ws, size_t ws_size,
                              hipStream_t stream) {
    const float* tgt    = (const float*)d_in[0];
    const float* pos    = (const float*)d_in[1];
    const float* refp   = (const float*)d_in[2];
    const float* memory = (const float*)d_in[3];
    const int*   shapes = (const int*)d_in[4];
    const int*   lsi    = (const int*)d_in[5];
    const float* sa_wq = (const float*)d_in[6],  *sa_bq = (const float*)d_in[7];
    const float* sa_wk = (const float*)d_in[8],  *sa_bk = (const float*)d_in[9];
    const float* sa_wv = (const float*)d_in[10], *sa_bv = (const float*)d_in[11];
    const float* sa_wo = (const float*)d_in[12], *sa_bo = (const float*)d_in[13];
    const float* ln2_g = (const float*)d_in[14], *ln2_b = (const float*)d_in[15];
    const float* ca_wval = (const float*)d_in[16], *ca_bval = (const float*)d_in[17];
    const float* ca_woff = (const float*)d_in[18], *ca_boff = (const float*)d_in[19];
    const float* ca_wattn = (const float*)d_in[20], *ca_battn = (const float*)d_in[21];
    const float* ca_wout = (const float*)d_in[22], *ca_bout = (const float*)d_in[23];
    const float* ln1_g = (const float*)d_in[24], *ln1_b = (const float*)d_in[25];
    const float* ffn_w1 = (const float*)d_in[26], *ffn_b1 = (const float*)d_in[27];
    const float* ffn_w2 = (const float*)d_in[28], *ffn_b2 = (const float*)d_in[29];
    const float* ln3_g = (const float*)d_in[30], *ln3_b = (const float*)d_in[31];
    float* out = (float*)d_out;

    // ---- workspace: bf16 area then f32 area ----
    ushort* wt = (ushort*)d_ws;
    ushort* wtq   = wt + 0;
    ushort* wtk   = wt + 65536;
    ushort* wtv   = wt + 131072;
    ushort* wto   = wt + 196608;
    ushort* wtval = wt + 262144;
    ushort* wtoff = wt + 327680;
    ushort* wtattn= wt + 393216;
    ushort* wtout = wt + 425984;
    ushort* wtf1  = wt + 491520;
    ushort* wtf2  = wt + 753664;
    const size_t MD = (size_t)MROWS * D;
    ushort* x_bf   = wt + 1015808;
    ushort* tgt_bf = x_bf + MD;
    ushort* q_bf   = tgt_bf + MD;
    ushort* k_bf   = q_bf + MD;
    ushort* v_bf   = k_bf + MD;
    ushort* o_bf   = v_bf + MD;
    ushort* value_bf = o_bf + MD;
    ushort* query_bf = x_bf;
    ushort* samp_bf  = tgt_bf;
    ushort* tgt2_bf  = q_bf;
    ushort* hbuf_bf  = value_bf;
    float* fws = (float*)(value_bf + (size_t)LV * BS * D);
    float* xo   = fws;
    float* tgt1 = xo + MD;
    float* tgt2 = tgt1 + MD;
    float* offs = tgt2 + MD;
    float* aw   = offs + MD;
    (void)ws_size; (void)in_sizes; (void)n_in; (void)out_size;

    dim3 b256(256);
    Job jz = {};
    auto mkb = [](const ushort* Xb, const ushort* Wt, const float* bias,
                  float* Yf, ushort* Yb, int M, int K, int N, int relu) {
        Job j; j.Xb = Xb; j.Xf = nullptr; j.Wt = Wt; j.bias = bias;
        j.Yf = Yf; j.Yb = Yb; j.M = M; j.K = K; j.N = N; j.relu = relu; return j;
    };

    // 1. weights
    wt_transpose_kernel<<<dim3(256, 1, 10), b256, 0, stream>>>(
        sa_wq, sa_wk, sa_wv, sa_wo, ca_wval, ca_woff, ca_wattn, ca_wout, ffn_w1, ffn_w2,
        wtq, wtk, wtv, wto, wtval, wtoff, wtattn, wtout, wtf1, wtf2);
    // 2. activations -> bf16
    prep_x_kernel<<<dim3(MD / 4 / 256), b256, 0, stream>>>(tgt, pos, x_bf, tgt_bf);
    // 3. q,k,v projections (batched)
    gemm_bf_kernel<<<dim3(4, 57, 3), b256, 0, stream>>>(
        mkb(x_bf, wtq, sa_bq, nullptr, q_bf, MROWS, D, D, 0),
        mkb(x_bf, wtk, sa_bk, nullptr, k_bf, MROWS, D, D, 0),
        mkb(tgt_bf, wtv, sa_bv, nullptr, v_bf, MROWS, D, D, 0));
    // 4. self attention
    sa_mfma_kernel<<<dim3(15, NH, BS), b256, 0, stream>>>(q_bf, k_bf, v_bf, o_bf);
    // 5. o-projection
    gemm_bf_kernel<<<dim3(4, 57, 1), b256, 0, stream>>>(
        mkb(o_bf, wto, sa_bo, xo, nullptr, MROWS, D, D, 0), jz, jz);
    // 6. LN2 (+ query_bf = bf(ln + pos))
    add_ln_kernel<2><<<dim3(MROWS), b256, 0, stream>>>(tgt, xo, ln2_g, ln2_b, tgt1, query_bf, pos);
    // 7. value projection (128-row tiles)
    gemm_wide_kernel<<<dim3((LV * BS + 127) / 128), dim3(512), 0, stream>>>(
        memory, wtval, ca_bval, value_bf, LV * BS);
    // 8. offsets + attention weights (batched; softmax fused into deform)
    gemm_bf_kernel<<<dim3(4, 57, 2), b256, 0, stream>>>(
        mkb(query_bf, wtoff, ca_boff, offs, nullptr, MROWS, D, 256, 0),
        mkb(query_bf, wtattn, ca_battn, aw, nullptr, MROWS, D, 128, 0), jz);
    // 9. deformable sampling (softmax inside, 2-phase)
    deform_kernel<<<dim3(NQ, BS), b256, 0, stream>>>(value_bf, offs, aw, refp, shapes, lsi, samp_bf);
    // 10. out-projection
    gemm_bf_kernel<<<dim3(4, 57, 1), b256, 0, stream>>>(
        mkb(samp_bf, wtout, ca_bout, xo, nullptr, MROWS, D, D, 0), jz, jz);
    // 11. LN1 (+ tgt2_bf)
    add_ln_kernel<1><<<dim3(MROWS), b256, 0, stream>>>(tgt1, xo, ln1_g, ln1_b, tgt2, tgt2_bf, nullptr);
    // 12. FFN1 (relu, bf16 out)
    gemm_bf_kernel<<<dim3(16, 57, 1), b256, 0, stream>>>(
        mkb(tgt2_bf, wtf1, ffn_b1, nullptr, hbuf_bf, MROWS, D, DFF, 1), jz, jz);
    // 13. FFN2
    gemm_bf_kernel<<<dim3(4, 57, 1), b256, 0, stream>>>(
        mkb(hbuf_bf, wtf2, ffn_b2, xo, nullptr, MROWS, DFF, D, 0), jz, jz);
    // 14. LN3 -> out
    add_ln_kernel<0><<<dim3(MROWS), b256, 0, stream>>>(tgt2, xo, ln3_g, ln3_b, out, nullptr, nullptr);
}

// Round 15
// 166.215 us; speedup vs baseline: 1.4957x; 1.2215x over previous
//
#include <hip/hip_runtime.h>

#define D    256
#define NH   8
#define DH   32
#define NL   4
#define NP   4
#define DFF  1024
#define NQ   900
#define BS   4
#define LV   13294
#define MROWS (NQ*BS)   // 3600

typedef short bf16x8 __attribute__((ext_vector_type(8)));
typedef float f32x4  __attribute__((ext_vector_type(4)));

__device__ inline ushort f2bf(float f) {
    unsigned u = __float_as_uint(f);
    unsigned r = (u + 0x7fffu + ((u >> 16) & 1u)) >> 16;
    return (ushort)r;
}
__device__ inline float bf2f(ushort u) { return __uint_as_float(((unsigned)u) << 16); }

// ---------------- prep: x_bf = bf(tgt+pos), tgt_bf = bf(tgt) ----------------
__global__ void prep_x_kernel(const float* __restrict__ tgt, const float* __restrict__ pos,
                              ushort* __restrict__ x_bf, ushort* __restrict__ tgt_bf) {
    int i = blockIdx.x * blockDim.x + threadIdx.x;
    float4 a = *(const float4*)&tgt[(size_t)i * 4];
    float4 p = *(const float4*)&pos[(size_t)i * 4];
    ushort4 xo, to;
    to.x = f2bf(a.x); to.y = f2bf(a.y); to.z = f2bf(a.z); to.w = f2bf(a.w);
    xo.x = f2bf(a.x + p.x); xo.y = f2bf(a.y + p.y); xo.z = f2bf(a.z + p.z); xo.w = f2bf(a.w + p.w);
    *(ushort4*)&x_bf[(size_t)i * 4] = xo;
    *(ushort4*)&tgt_bf[(size_t)i * 4] = to;
}

// ---------------- weight transpose+convert: W[K][N] f32 -> Wt[N][K] bf16 ----------------
__global__ void wt_transpose_kernel(
    const float* w0, const float* w1, const float* w2, const float* w3, const float* w4,
    const float* w5, const float* w6, const float* w7, const float* w8, const float* w9,
    ushort* o0, ushort* o1, ushort* o2, ushort* o3, ushort* o4,
    ushort* o5, ushort* o6, ushort* o7, ushort* o8, ushort* o9) {
    __shared__ float Ts[32][33];
    int z = blockIdx.z;
    const float* src; ushort* dst; int K, N;
    switch (z) {
        case 0: src = w0; dst = o0; K = 256;  N = 256;  break;
        case 1: src = w1; dst = o1; K = 256;  N = 256;  break;
        case 2: src = w2; dst = o2; K = 256;  N = 256;  break;
        case 3: src = w3; dst = o3; K = 256;  N = 256;  break;
        case 4: src = w4; dst = o4; K = 256;  N = 256;  break;
        case 5: src = w5; dst = o5; K = 256;  N = 256;  break;
        case 6: src = w6; dst = o6; K = 256;  N = 128;  break;
        case 7: src = w7; dst = o7; K = 256;  N = 256;  break;
        case 8: src = w8; dst = o8; K = 256;  N = 1024; break;
        default:src = w9; dst = o9; K = 1024; N = 256;  break;
    }
    int tiles_n = N >> 5;
    int tile = blockIdx.x;
    int tx = tile % tiles_n, ty = tile / tiles_n;
    if (ty >= (K >> 5)) return;
    int n0 = tx * 32, k0 = ty * 32;
    int t = threadIdx.x;
    #pragma unroll
    for (int i = 0; i < 4; ++i) {
        int e = t + i * 256; int r = e >> 5, c = e & 31;
        Ts[r][c] = src[(size_t)(k0 + r) * N + n0 + c];
    }
    __syncthreads();
    #pragma unroll
    for (int i = 0; i < 4; ++i) {
        int e = t + i * 256; int r = e >> 5, c = e & 31;
        dst[(size_t)(n0 + r) * K + k0 + c] = f2bf(Ts[c][r]);
    }
}

// ---------------- bf16 MFMA GEMM: Y[M,N] = X[M,K] @ Wt[N,K]^T + bias ----------------
struct Job {
    const ushort* Xb;
    const float*  Xf;
    const ushort* Wt;
    const float*  bias;
    float*  Yf;
    ushort* Yb;
    int M, K, N, relu;
};

__global__ __launch_bounds__(256, 3)
void gemm_bf_kernel(Job j0, Job j1, Job j2) {
    Job j = (blockIdx.z == 0) ? j0 : (blockIdx.z == 1 ? j1 : j2);
    const int row0 = blockIdx.y * 64, col0 = blockIdx.x * 64;
    if (row0 >= j.M || col0 >= j.N) return;
    __shared__ ushort As[64 * 72];
    __shared__ ushort Bs[64 * 72];
    const int t = threadIdx.x, w = t >> 6, lane = t & 63;
    const int wr = w >> 1, wc = w & 1, l15 = lane & 15, kb = lane >> 4;

    f32x4 acc[2][2];
    #pragma unroll
    for (int i = 0; i < 2; ++i)
        #pragma unroll
        for (int jj = 0; jj < 2; ++jj) acc[i][jj] = (f32x4){0.f, 0.f, 0.f, 0.f};

    uint4 ra0, ra1, rb0, rb1;
    float4 rf0, rf1, rf2, rf3;

    auto gload = [&](int k0) {
        if (j.Xb) {
            {
                int e = t;              int row = e >> 3, c = e & 7;
                int gr = row0 + row; if (gr >= j.M) gr = j.M - 1;
                ra0 = *(const uint4*)&j.Xb[(size_t)gr * j.K + k0 + c * 8];
            }
            {
                int e = t + 256;        int row = e >> 3, c = e & 7;
                int gr = row0 + row; if (gr >= j.M) gr = j.M - 1;
                ra1 = *(const uint4*)&j.Xb[(size_t)gr * j.K + k0 + c * 8];
            }
        } else {
            {
                int e = t;              int row = e >> 4, q = e & 15;
                int gr = row0 + row; if (gr >= j.M) gr = j.M - 1;
                rf0 = *(const float4*)&j.Xf[(size_t)gr * j.K + k0 + q * 4];
            }
            {
                int e = t + 256;        int row = e >> 4, q = e & 15;
                int gr = row0 + row; if (gr >= j.M) gr = j.M - 1;
                rf1 = *(const float4*)&j.Xf[(size_t)gr * j.K + k0 + q * 4];
            }
            {
                int e = t + 512;        int row = e >> 4, q = e & 15;
                int gr = row0 + row; if (gr >= j.M) gr = j.M - 1;
                rf2 = *(const float4*)&j.Xf[(size_t)gr * j.K + k0 + q * 4];
            }
            {
                int e = t + 768;        int row = e >> 4, q = e & 15;
                int gr = row0 + row; if (gr >= j.M) gr = j.M - 1;
                rf3 = *(const float4*)&j.Xf[(size_t)gr * j.K + k0 + q * 4];
            }
        }
        {
            int e = t;                  int row = e >> 3, c = e & 7;
            rb0 = *(const uint4*)&j.Wt[(size_t)(col0 + row) * j.K + k0 + c * 8];
        }
        {
            int e = t + 256;            int row = e >> 3, c = e & 7;
            rb1 = *(const uint4*)&j.Wt[(size_t)(col0 + row) * j.K + k0 + c * 8];
        }
    };
    auto cvt4 = [](float4 f) {
        ushort4 pk;
        pk.x = f2bf(f.x); pk.y = f2bf(f.y); pk.z = f2bf(f.z); pk.w = f2bf(f.w);
        return pk;
    };
    auto lwrite = [&]() {
        if (j.Xb) {
            { int e = t;       int row = e >> 3, c = e & 7; *(uint4*)&As[row * 72 + c * 8] = ra0; }
            { int e = t + 256; int row = e >> 3, c = e & 7; *(uint4*)&As[row * 72 + c * 8] = ra1; }
        } else {
            { int e = t;       int row = e >> 4, q = e & 15; *(ushort4*)&As[row * 72 + q * 4] = cvt4(rf0); }
            { int e = t + 256; int row = e >> 4, q = e & 15; *(ushort4*)&As[row * 72 + q * 4] = cvt4(rf1); }
            { int e = t + 512; int row = e >> 4, q = e & 15; *(ushort4*)&As[row * 72 + q * 4] = cvt4(rf2); }
            { int e = t + 768; int row = e >> 4, q = e & 15; *(ushort4*)&As[row * 72 + q * 4] = cvt4(rf3); }
        }
        { int e = t;       int row = e >> 3, c = e & 7; *(uint4*)&Bs[row * 72 + c * 8] = rb0; }
        { int e = t + 256; int row = e >> 3, c = e & 7; *(uint4*)&Bs[row * 72 + c * 8] = rb1; }
    };
    auto compute = [&]() {
        bf16x8 a[2][2], b[2][2];
        #pragma unroll
        for (int i = 0; i < 2; ++i)
            #pragma unroll
            for (int kh = 0; kh < 2; ++kh)
                a[i][kh] = *(const bf16x8*)&As[(wr * 32 + i * 16 + l15) * 72 + (kh * 4 + kb) * 8];
        #pragma unroll
        for (int jj = 0; jj < 2; ++jj)
            #pragma unroll
            for (int kh = 0; kh < 2; ++kh)
                b[jj][kh] = *(const bf16x8*)&Bs[(wc * 32 + jj * 16 + l15) * 72 + (kh * 4 + kb) * 8];
        #pragma unroll
        for (int kh = 0; kh < 2; ++kh)
            #pragma unroll
            for (int i = 0; i < 2; ++i)
                #pragma unroll
                for (int jj = 0; jj < 2; ++jj)
                    acc[i][jj] = __builtin_amdgcn_mfma_f32_16x16x32_bf16(
                        a[i][kh], b[jj][kh], acc[i][jj], 0, 0, 0);
    };

    gload(0);
    lwrite();
    __syncthreads();
    const int nt = j.K >> 6;
    for (int tt = 0; tt < nt; ++tt) {
        if (tt + 1 < nt) gload((tt + 1) << 6);
        compute();
        __syncthreads();
        if (tt + 1 < nt) { lwrite(); __syncthreads(); }
    }

    if (j.Yb) {
        #pragma unroll
        for (int i = 0; i < 2; ++i) {
            #pragma unroll
            for (int jj = 0; jj < 2; ++jj) {
                int lcol = wc * 32 + jj * 16 + l15;
                float bv = j.bias[col0 + lcol];
                #pragma unroll
                for (int r = 0; r < 4; ++r) {
                    int lrow = wr * 32 + i * 16 + kb * 4 + r;
                    float vv = acc[i][jj][r] + bv;
                    if (j.relu) vv = fmaxf(vv, 0.f);
                    As[lrow * 64 + lcol] = f2bf(vv);
                }
            }
        }
        __syncthreads();
        #pragma unroll
        for (int it = 0; it < 2; ++it) {
            int idx = t + it * 256;
            int lrow = idx >> 3, c = idx & 7;
            int grow = row0 + lrow;
            if (grow < j.M)
                *(uint4*)&j.Yb[(size_t)grow * j.N + col0 + c * 8] =
                    *(const uint4*)&As[lrow * 64 + c * 8];
        }
    } else {
        #pragma unroll
        for (int i = 0; i < 2; ++i) {
            #pragma unroll
            for (int jj = 0; jj < 2; ++jj) {
                int gcol = col0 + wc * 32 + jj * 16 + l15;
                float bv = j.bias[gcol];
                #pragma unroll
                for (int r = 0; r < 4; ++r) {
                    int grow = row0 + wr * 32 + i * 16 + kb * 4 + r;
                    if (grow < j.M) {
                        float vv = acc[i][jj][r] + bv;
                        if (j.relu) vv = fmaxf(vv, 0.f);
                        j.Yf[(size_t)grow * j.N + gcol] = vv;
                    }
                }
            }
        }
    }
}

// ---------------- wide GEMM for value projection: Y[M,256] = X[M,256](f32) @ Wt^T ----------------
// 128-row x 256-col tile, 512 threads (8 waves, 2x4 of 64x64), 416 blocks.
__global__ __launch_bounds__(512, 2)
void gemm_wide_kernel(const float* __restrict__ Xf, const ushort* __restrict__ Wt,
                      const float* __restrict__ bias, ushort* __restrict__ Yb, int M) {
    __shared__ ushort As[128 * 72];
    __shared__ ushort Bs[256 * 72];
    const int t = threadIdx.x, w = t >> 6, lane = t & 63;
    const int wr = w >> 2, wc = w & 3, l15 = lane & 15, kb = lane >> 4;
    const int row0 = blockIdx.x * 128;

    f32x4 acc[4][4];
    #pragma unroll
    for (int i = 0; i < 4; ++i)
        #pragma unroll
        for (int jj = 0; jj < 4; ++jj) acc[i][jj] = (f32x4){0.f, 0.f, 0.f, 0.f};

    float4 rf[4];
    uint4 rb[4];

    auto gload = [&](int k0) {
        #pragma unroll
        for (int i = 0; i < 4; ++i) {
            int e = t + i * 512; int row = e >> 4, q = e & 15;
            int gr = row0 + row; if (gr >= M) gr = M - 1;
            rf[i] = *(const float4*)&Xf[(size_t)gr * 256 + k0 + q * 4];
        }
        #pragma unroll
        for (int i = 0; i < 4; ++i) {
            int e = t + i * 512; int row = e >> 3, c = e & 7;
            rb[i] = *(const uint4*)&Wt[(size_t)row * 256 + k0 + c * 8];
        }
    };
    auto cvt4 = [](float4 f) {
        ushort4 pk;
        pk.x = f2bf(f.x); pk.y = f2bf(f.y); pk.z = f2bf(f.z); pk.w = f2bf(f.w);
        return pk;
    };
    auto lwrite = [&]() {
        #pragma unroll
        for (int i = 0; i < 4; ++i) {
            int e = t + i * 512; int row = e >> 4, q = e & 15;
            *(ushort4*)&As[row * 72 + q * 4] = cvt4(rf[i]);
        }
        #pragma unroll
        for (int i = 0; i < 4; ++i) {
            int e = t + i * 512; int row = e >> 3, c = e & 7;
            *(uint4*)&Bs[row * 72 + c * 8] = rb[i];
        }
    };
    auto compute = [&]() {
        bf16x8 a[4][2], b[4][2];
        #pragma unroll
        for (int i = 0; i < 4; ++i)
            #pragma unroll
            for (int kh = 0; kh < 2; ++kh)
                a[i][kh] = *(const bf16x8*)&As[(wr * 64 + i * 16 + l15) * 72 + (kh * 4 + kb) * 8];
        #pragma unroll
        for (int jj = 0; jj < 4; ++jj)
            #pragma unroll
            for (int kh = 0; kh < 2; ++kh)
                b[jj][kh] = *(const bf16x8*)&Bs[(wc * 64 + jj * 16 + l15) * 72 + (kh * 4 + kb) * 8];
        #pragma unroll
        for (int kh = 0; kh < 2; ++kh)
            #pragma unroll
            for (int i = 0; i < 4; ++i)
                #pragma unroll
                for (int jj = 0; jj < 4; ++jj)
                    acc[i][jj] = __builtin_amdgcn_mfma_f32_16x16x32_bf16(
                        a[i][kh], b[jj][kh], acc[i][jj], 0, 0, 0);
    };

    gload(0);
    lwrite();
    __syncthreads();
    #pragma unroll
    for (int tt = 0; tt < 4; ++tt) {
        if (tt + 1 < 4) gload((tt + 1) << 6);
        compute();
        __syncthreads();
        if (tt + 1 < 4) { lwrite(); __syncthreads(); }
    }

    // epilogue: two 64-row halves staged through Bs (32 KB each), coalesced stores
    ushort* obuf = Bs;
    #pragma unroll
    for (int half = 0; half < 2; ++half) {
        if (wr == half) {
            #pragma unroll
            for (int i = 0; i < 4; ++i) {
                #pragma unroll
                for (int jj = 0; jj < 4; ++jj) {
                    int lcol = wc * 64 + jj * 16 + l15;
                    float bv = bias[lcol];
                    #pragma unroll
                    for (int r = 0; r < 4; ++r) {
                        int lrow = i * 16 + kb * 4 + r;   // 0..63
                        obuf[lrow * 256 + lcol] = f2bf(acc[i][jj][r] + bv);
                    }
                }
            }
        }
        __syncthreads();
        #pragma unroll
        for (int it = 0; it < 4; ++it) {
            int idx = t + it * 512;           // 2048 uint4 = 64 rows x 32
            int lrow = idx >> 5, c = idx & 31;
            int grow = row0 + half * 64 + lrow;
            if (grow < M)
                *(uint4*)&Yb[(size_t)grow * 256 + c * 8] =
                    *(const uint4*)&obuf[lrow * 256 + c * 8];
        }
        __syncthreads();
    }
}

// ---------------- MFMA flash self-attention (bf16 in/out) ----------------
__global__ __launch_bounds__(256, 2)
void sa_mfma_kernel(const ushort* __restrict__ q, const ushort* __restrict__ k,
                    const ushort* __restrict__ v, ushort* __restrict__ o) {
    __shared__ ushort Qs[64 * 40];
    __shared__ ushort Ks[64 * 40];
    __shared__ ushort Vt[32 * 72];
    __shared__ ushort Pw[4 * 16 * 72];
    const int qt = blockIdx.x, h = blockIdx.y, b = blockIdx.z;
    const int q0 = qt * 64, t = threadIdx.x;
    const int w = t >> 6, lane = t & 63;
    const int l15 = lane & 15, kb = lane >> 4;
    const float scale = 0.17677669529663687f;

    {
        int row = t >> 2, c = t & 3;
        int qn = min(q0 + row, NQ - 1);
        *(uint4*)&Qs[row * 40 + c * 8] =
            *(const uint4*)&q[((size_t)qn * BS + b) * D + h * DH + c * 8];
    }
    float m_run[4], l_run[4];
    #pragma unroll
    for (int r = 0; r < 4; ++r) { m_run[r] = -1e30f; l_run[r] = 0.f; }
    f32x4 oacc[2];
    oacc[0] = (f32x4){0.f, 0.f, 0.f, 0.f};
    oacc[1] = (f32x4){0.f, 0.f, 0.f, 0.f};
    __syncthreads();

    for (int k0 = 0; k0 < NQ; k0 += 64) {
        {
            int row = t >> 2, c = t & 3;
            int kn = min(k0 + row, NQ - 1);
            *(uint4*)&Ks[row * 40 + c * 8] =
                *(const uint4*)&k[((size_t)kn * BS + b) * D + h * DH + c * 8];
            uint4 vv = *(const uint4*)&v[((size_t)kn * BS + b) * D + h * DH + c * 8];
            ushort* pv = (ushort*)&vv;
            #pragma unroll
            for (int u = 0; u < 8; ++u) Vt[(c * 8 + u) * 72 + row] = pv[u];
        }
        __syncthreads();

        bf16x8 aq = *(const bf16x8*)&Qs[(w * 16 + l15) * 40 + kb * 8];
        f32x4 sacc[4];
        #pragma unroll
        for (int jj = 0; jj < 4; ++jj) {
            bf16x8 bk = *(const bf16x8*)&Ks[(jj * 16 + l15) * 40 + kb * 8];
            sacc[jj] = __builtin_amdgcn_mfma_f32_16x16x32_bf16(
                aq, bk, (f32x4){0.f, 0.f, 0.f, 0.f}, 0, 0, 0);
        }
        int kvalid = NQ - k0;
        #pragma unroll
        for (int jj = 0; jj < 4; ++jj) {
            #pragma unroll
            for (int r = 0; r < 4; ++r) sacc[jj][r] *= scale;
            if (jj * 16 + l15 >= kvalid) {
                #pragma unroll
                for (int r = 0; r < 4; ++r) sacc[jj][r] = -1e30f;
            }
        }
        float tm[4];
        #pragma unroll
        for (int r = 0; r < 4; ++r)
            tm[r] = fmaxf(fmaxf(sacc[0][r], sacc[1][r]), fmaxf(sacc[2][r], sacc[3][r]));
        #pragma unroll
        for (int msk = 1; msk <= 8; msk <<= 1)
            #pragma unroll
            for (int r = 0; r < 4; ++r) tm[r] = fmaxf(tm[r], __shfl_xor(tm[r], msk));
        float scl[4], newm[4];
        #pragma unroll
        for (int r = 0; r < 4; ++r) {
            newm[r] = fmaxf(m_run[r], tm[r]);
            scl[r] = __expf(m_run[r] - newm[r]);
            m_run[r] = newm[r];
        }
        float ps[4] = {0.f, 0.f, 0.f, 0.f};
        #pragma unroll
        for (int jj = 0; jj < 4; ++jj) {
            #pragma unroll
            for (int r = 0; r < 4; ++r) {
                float p = __expf(sacc[jj][r] - newm[r]);
                ps[r] += p;
                Pw[w * 1152 + (kb * 4 + r) * 72 + jj * 16 + l15] = f2bf(p);
            }
        }
        #pragma unroll
        for (int msk = 1; msk <= 8; msk <<= 1)
            #pragma unroll
            for (int r = 0; r < 4; ++r) ps[r] += __shfl_xor(ps[r], msk);
        #pragma unroll
        for (int r = 0; r < 4; ++r) l_run[r] = l_run[r] * scl[r] + ps[r];
        #pragma unroll
        for (int df = 0; df < 2; ++df)
            #pragma unroll
            for (int r = 0; r < 4; ++r) oacc[df][r] *= scl[r];
        #pragma unroll
        for (int hf = 0; hf < 2; ++hf) {
            bf16x8 pa = *(const bf16x8*)&Pw[w * 1152 + l15 * 72 + hf * 32 + kb * 8];
            #pragma unroll
            for (int df = 0; df < 2; ++df) {
                bf16x8 vb = *(const bf16x8*)&Vt[(df * 16 + l15) * 72 + hf * 32 + kb * 8];
                oacc[df] = __builtin_amdgcn_mfma_f32_16x16x32_bf16(pa, vb, oacc[df], 0, 0, 0);
            }
        }
        __syncthreads();
    }
    #pragma unroll
    for (int df = 0; df < 2; ++df) {
        #pragma unroll
        for (int r = 0; r < 4; ++r) {
            int qg = q0 + w * 16 + kb * 4 + r;
            if (qg < NQ)
                o[((size_t)qg * BS + b) * D + h * DH + df * 16 + l15] =
                    f2bf(oacc[df][r] / l_run[r]);
        }
    }
}

// ---------------- out = LayerNorm(x + y); MODE 0: f32; 1: +bf16; 2: +bf16(ln+pos) ----------------
template<int MODE>
__global__ void add_ln_kernel(const float* __restrict__ x, const float* __restrict__ y,
                              const float* __restrict__ g, const float* __restrict__ bt,
                              float* __restrict__ outf, ushort* __restrict__ outb,
                              const float* __restrict__ pos) {
    int m = blockIdx.x, t = threadIdx.x;
    __shared__ float red[8];
    float v = x[m * D + t] + y[m * D + t];
    int lane = t & 63, wid = t >> 6;
    float s = v;
    for (int off = 32; off; off >>= 1) s += __shfl_down(s, off);
    if (lane == 0) red[wid] = s;
    __syncthreads();
    if (t == 0) red[4] = (red[0] + red[1] + red[2] + red[3]) * (1.f / D);
    __syncthreads();
    float mu = red[4];
    float d = v - mu;
    float s2 = d * d;
    __syncthreads();
    for (int off = 32; off; off >>= 1) s2 += __shfl_down(s2, off);
    if (lane == 0) red[wid] = s2;
    __syncthreads();
    if (t == 0) red[5] = rsqrtf((red[0] + red[1] + red[2] + red[3]) * (1.f / D) + 1e-5f);
    __syncthreads();
    float res = d * red[5] * g[t] + bt[t];
    outf[m * D + t] = res;
    if (MODE == 1) outb[m * D + t] = f2bf(res);
    if (MODE == 2) outb[m * D + t] = f2bf(res + pos[m * D + t]);
}

// ---------------- deformable sampling: 2-phase, batched gathers for MLP ----------------
__global__ __launch_bounds__(256, 4)
void deform_kernel(const ushort* __restrict__ value, const float* __restrict__ offs,
                   const float* __restrict__ aw, const float* __restrict__ refp,
                   const int* __restrict__ shapes, const int* __restrict__ lsi,
                   ushort* __restrict__ outb) {
    int n = blockIdx.x, b = blockIdx.y;
    int t = threadIdx.x;
    int m = n * BS + b;
    __shared__ float awn[NH * 16];
    __shared__ int4  sadr[128];
    __shared__ float4 swt[128];
    if (t < NH) {
        const float* p = aw + (size_t)m * 128 + t * 16;
        float mx = p[0];
        #pragma unroll
        for (int jj = 1; jj < 16; ++jj) mx = fmaxf(mx, p[jj]);
        float e[16], s = 0.f;
        #pragma unroll
        for (int jj = 0; jj < 16; ++jj) { e[jj] = __expf(p[jj] - mx); s += e[jj]; }
        float inv = 1.f / s;
        #pragma unroll
        for (int jj = 0; jj < 16; ++jj) awn[t * 16 + jj] = e[jj] * inv;
    }
    __syncthreads();
    if (t < 128) {
        int h = t >> 4, l = (t >> 2) & 3, p = t & 3;
        int Hl = shapes[l * 2], Wl = shapes[l * 2 + 1], s = lsi[l];
        float Wf = (float)Wl, Hf = (float)Hl;
        float rx = refp[(m * NL + l) * 2 + 0];
        float ry = refp[(m * NL + l) * 2 + 1];
        int oc = ((h * NL + l) * NP + p) * 2;
        float ox = offs[m * 256 + oc];
        float oy = offs[m * 256 + oc + 1];
        float ww = awn[h * 16 + l * NP + p];
        float x = (rx + ox / Wf) * Wf - 0.5f;
        float y = (ry + oy / Hf) * Hf - 0.5f;
        float x0 = floorf(x), y0 = floorf(y);
        float lx = x - x0, ly = y - y0;
        int xi = (int)x0, yi = (int)y0;
        int4 a4; float4 w4;
        int* ap = (int*)&a4; float* wp = (float*)&w4;
        #pragma unroll
        for (int cy = 0; cy < 2; ++cy) {
            #pragma unroll
            for (int cx = 0; cx < 2; ++cx) {
                int xx = xi + cx, yy = yi + cy;
                bool valid = (xx >= 0 && xx < Wl && yy >= 0 && yy < Hl);
                float cw = (cx ? lx : 1.f - lx) * (cy ? ly : 1.f - ly);
                ap[cy * 2 + cx] = valid ? (int)(((size_t)(s + yy * Wl + xx) * BS + b) * D + h * DH) : 0;
                wp[cy * 2 + cx] = valid ? ww * cw : 0.f;
            }
        }
        sadr[t] = a4;
        swt[t] = w4;
    }
    __syncthreads();
    int h = t >> 5, dh = t & 31;
    float acc = 0.f;
    // batch 8 samples: issue 32 loads, then 32 FMAs -> deep memory pipeline
    #pragma unroll
    for (int i0 = 0; i0 < 16; i0 += 8) {
        float v[32];
        #pragma unroll
        for (int s8 = 0; s8 < 8; ++s8) {
            int4 a4 = sadr[h * 16 + i0 + s8];
            v[s8 * 4 + 0] = bf2f(value[a4.x + dh]);
            v[s8 * 4 + 1] = bf2f(value[a4.y + dh]);
            v[s8 * 4 + 2] = bf2f(value[a4.z + dh]);
            v[s8 * 4 + 3] = bf2f(value[a4.w + dh]);
        }
        #pragma unroll
        for (int s8 = 0; s8 < 8; ++s8) {
            float4 w4 = swt[h * 16 + i0 + s8];
            acc += w4.x * v[s8 * 4 + 0] + w4.y * v[s8 * 4 + 1]
                 + w4.z * v[s8 * 4 + 2] + w4.w * v[s8 * 4 + 3];
        }
    }
    outb[m * D + h * DH + dh] = f2bf(acc);
}

extern "C" void kernel_launch(void* const* d_in, const int* in_sizes, int n_in,
                              void* d_out, int out_size, void* d_ws, size_t ws_size,
                              hipStream_t stream) {
    const float* tgt    = (const float*)d_in[0];
    const float* pos    = (const float*)d_in[1];
    const float* refp   = (const float*)d_in[2];
    const float* memory = (const float*)d_in[3];
    const int*   shapes = (const int*)d_in[4];
    const int*   lsi    = (const int*)d_in[5];
    const float* sa_wq = (const float*)d_in[6],  *sa_bq = (const float*)d_in[7];
    const float* sa_wk = (const float*)d_in[8],  *sa_bk = (const float*)d_in[9];
    const float* sa_wv = (const float*)d_in[10], *sa_bv = (const float*)d_in[11];
    const float* sa_wo = (const float*)d_in[12], *sa_bo = (const float*)d_in[13];
    const float* ln2_g = (const float*)d_in[14], *ln2_b = (const float*)d_in[15];
    const float* ca_wval = (const float*)d_in[16], *ca_bval = (const float*)d_in[17];
    const float* ca_woff = (const float*)d_in[18], *ca_boff = (const float*)d_in[19];
    const float* ca_wattn = (const float*)d_in[20], *ca_battn = (const float*)d_in[21];
    const float* ca_wout = (const float*)d_in[22], *ca_bout = (const float*)d_in[23];
    const float* ln1_g = (const float*)d_in[24], *ln1_b = (const float*)d_in[25];
    const float* ffn_w1 = (const float*)d_in[26], *ffn_b1 = (const float*)d_in[27];
    const float* ffn_w2 = (const float*)d_in[28], *ffn_b2 = (const float*)d_in[29];
    const float* ln3_g = (const float*)d_in[30], *ln3_b = (const float*)d_in[31];
    float* out = (float*)d_out;

    // ---- workspace: bf16 area then f32 area ----
    ushort* wt = (ushort*)d_ws;
    ushort* wtq   = wt + 0;
    ushort* wtk   = wt + 65536;
    ushort* wtv   = wt + 131072;
    ushort* wto   = wt + 196608;
    ushort* wtval = wt + 262144;
    ushort* wtoff = wt + 327680;
    ushort* wtattn= wt + 393216;
    ushort* wtout = wt + 425984;
    ushort* wtf1  = wt + 491520;
    ushort* wtf2  = wt + 753664;
    const size_t MD = (size_t)MROWS * D;
    ushort* x_bf   = wt + 1015808;
    ushort* tgt_bf = x_bf + MD;
    ushort* q_bf   = tgt_bf + MD;
    ushort* k_bf   = q_bf + MD;
    ushort* v_bf   = k_bf + MD;
    ushort* o_bf   = v_bf + MD;
    ushort* value_bf = o_bf + MD;
    ushort* query_bf = x_bf;
    ushort* samp_bf  = tgt_bf;
    ushort* tgt2_bf  = q_bf;
    ushort* hbuf_bf  = value_bf;
    float* fws = (float*)(value_bf + (size_t)LV * BS * D);
    float* xo   = fws;
    float* tgt1 = xo + MD;
    float* tgt2 = tgt1 + MD;
    float* offs = tgt2 + MD;
    float* aw   = offs + MD;
    (void)ws_size; (void)in_sizes; (void)n_in; (void)out_size;

    dim3 b256(256);
    Job jz = {};
    auto mkb = [](const ushort* Xb, const ushort* Wt, const float* bias,
                  float* Yf, ushort* Yb, int M, int K, int N, int relu) {
        Job j; j.Xb = Xb; j.Xf = nullptr; j.Wt = Wt; j.bias = bias;
        j.Yf = Yf; j.Yb = Yb; j.M = M; j.K = K; j.N = N; j.relu = relu; return j;
    };

    // 1. weights
    wt_transpose_kernel<<<dim3(256, 1, 10), b256, 0, stream>>>(
        sa_wq, sa_wk, sa_wv, sa_wo, ca_wval, ca_woff, ca_wattn, ca_wout, ffn_w1, ffn_w2,
        wtq, wtk, wtv, wto, wtval, wtoff, wtattn, wtout, wtf1, wtf2);
    // 2. activations -> bf16
    prep_x_kernel<<<dim3(MD / 4 / 256), b256, 0, stream>>>(tgt, pos, x_bf, tgt_bf);
    // 3. q,k,v projections (batched)
    gemm_bf_kernel<<<dim3(4, 57, 3), b256, 0, stream>>>(
        mkb(x_bf, wtq, sa_bq, nullptr, q_bf, MROWS, D, D, 0),
        mkb(x_bf, wtk, sa_bk, nullptr, k_bf, MROWS, D, D, 0),
        mkb(tgt_bf, wtv, sa_bv, nullptr, v_bf, MROWS, D, D, 0));
    // 4. self attention
    sa_mfma_kernel<<<dim3(15, NH, BS), b256, 0, stream>>>(q_bf, k_bf, v_bf, o_bf);
    // 5. o-projection
    gemm_bf_kernel<<<dim3(4, 57, 1), b256, 0, stream>>>(
        mkb(o_bf, wto, sa_bo, xo, nullptr, MROWS, D, D, 0), jz, jz);
    // 6. LN2 (+ query_bf = bf(ln + pos))
    add_ln_kernel<2><<<dim3(MROWS), b256, 0, stream>>>(tgt, xo, ln2_g, ln2_b, tgt1, query_bf, pos);
    // 7. value projection (128-row tiles)
    gemm_wide_kernel<<<dim3((LV * BS + 127) / 128), dim3(512), 0, stream>>>(
        memory, wtval, ca_bval, value_bf, LV * BS);
    // 8. offsets + attention weights (batched; softmax fused into deform)
    gemm_bf_kernel<<<dim3(4, 57, 2), b256, 0, stream>>>(
        mkb(query_bf, wtoff, ca_boff, offs, nullptr, MROWS, D, 256, 0),
        mkb(query_bf, wtattn, ca_battn, aw, nullptr, MROWS, D, 128, 0), jz);
    // 9. deformable sampling (softmax inside, 2-phase, batched gathers)
    deform_kernel<<<dim3(NQ, BS), b256, 0, stream>>>(value_bf, offs, aw, refp, shapes, lsi, samp_bf);
    // 10. out-projection
    gemm_bf_kernel<<<dim3(4, 57, 1), b256, 0, stream>>>(
        mkb(samp_bf, wtout, ca_bout, xo, nullptr, MROWS, D, D, 0), jz, jz);
    // 11. LN1 (+ tgt2_bf)
    add_ln_kernel<1><<<dim3(MROWS), b256, 0, stream>>>(tgt1, xo, ln1_g, ln1_b, tgt2, tgt2_bf, nullptr);
    // 12. FFN1 (relu, bf16 out)
    gemm_bf_kernel<<<dim3(16, 57, 1), b256, 0, stream>>>(
        mkb(tgt2_bf, wtf1, ffn_b1, nullptr, hbuf_bf, MROWS, D, DFF, 1), jz, jz);
    // 13. FFN2
    gemm_bf_kernel<<<dim3(4, 57, 1), b256, 0, stream>>>(
        mkb(hbuf_bf, wtf2, ffn_b2, xo, nullptr, MROWS, DFF, D, 0), jz, jz);
    // 14. LN3 -> out
    add_ln_kernel<0><<<dim3(MROWS), b256, 0, stream>>>(tgt2, xo, ln3_g, ln3_b, out, nullptr, nullptr);
}